// Round 5
// baseline (356.299 us; speedup 1.0000x reference)
//
#include <hip/hip_runtime.h>
#include <hip/hip_bf16.h>

#define H 256
#define KNN 16
#define NPT 256
#define BB 64

typedef unsigned short u16;
typedef unsigned int u32;
typedef __attribute__((ext_vector_type(8))) short shortx8;
typedef __attribute__((ext_vector_type(4))) float floatx4;

// RNE f32->bf16 via hw cvt; same rounding as manual (u + 0x7fff + lsb) >> 16.
__device__ __forceinline__ u16 f2b(float f) {
    return __builtin_bit_cast(u16, __float2bfloat16(f));
}
__device__ __forceinline__ float b2f(u16 u) {
    return __uint_as_float(((u32)u) << 16);
}

// tanh via hw exp2: 1 - 2/(exp2(x*2log2e)+1). |err| ~1e-6, saturates correctly.
__device__ __forceinline__ float fast_tanh(float x) {
    float e = __builtin_amdgcn_exp2f(x * 2.88539008177793f);
    return 1.0f - 2.0f * __builtin_amdgcn_rcpf(e + 1.0f);
}

// ---------------------------------------------------------------------------
// Session ledger:
// R10: edge M=64, interleaved scalar gathers: 146us. PROVEN GOOD.
// R11: edge register gather-prefetch: spills at (256,4)'s 128-reg cap, +75us.
// R12: edge global_load_lds staging: +2 serializing barriers, +4us. Gathers
//      were never the cost.
// R13: edge M=32: occupancy 41->64% but per-block fixed cost dominates,
//      +92us. Edge is NOT occupancy-bound.
// R14: edge epilogue reorder: 146->138us. Total 338. CONFIRMED.
// R15: featB eliminated (ws -8MB): total -2us only -> reset cost NOT ~ ws
//      bytes. setprio: null (lockstep GEMM, matches m190). Edge 137us.
// KEY REGRESSION FACT: total = edge + ~200us across ALL rounds; non-edge
//      time is stable and invisible (top-5 all edge). R16 attacks the three
//      inspectable defects in that 200us: prep's uncoalesced transposed
//      reads (LDS tiled transpose), msg at 1 block/CU (-> 32pts/block,
//      2/CU), out at 2 blocks/CU (-> 16pts/block, 4/CU). All value-exact.
// ---------------------------------------------------------------------------
// K0: prep — LDS 64x64 tiled transpose, coalesced both sides, [64][66] u16
// pad = conflict-free transposed read. Blocks 0..71 = tiles of
// {w2,we1,wm,wo}; block 72 = w1t special (tiny).
// ---------------------------------------------------------------------------
__global__ __launch_bounds__(256) void prep_kernel(
    const float* __restrict__ w2, const float* __restrict__ we1,
    const float* __restrict__ wm, const float* __restrict__ wo,
    const float* __restrict__ w1, const float* __restrict__ b1,
    u16* __restrict__ w2t, u16* __restrict__ we1t,
    u16* __restrict__ wmt, u16* __restrict__ wot, u16* __restrict__ w1t) {
    int bid = blockIdx.x, t = threadIdx.x;
    if (bid == 72) {  // w1t: 256 x 32, k<4 from w1, k==4 bias row, else 0
        for (int e = t; e < 8192; e += 256) {
            int n = e >> 5, k = e & 31;
            float v = (k < 4) ? w1[k * 256 + n] : (k == 4 ? b1[n] : 0.0f);
            w1t[e] = f2b(v);
        }
        return;
    }
    const float* in; u16* outp; int K, N, kt, nt;
    if (bid < 16)      { in = w2;  outp = w2t;  K = 256; N = 256; int q = bid;      kt = q >> 2; nt = q & 3; }
    else if (bid < 24) { in = we1; outp = we1t; K = 256; N = 128; int q = bid - 16; kt = q >> 1; nt = q & 1; }
    else if (bid < 40) { in = wm;  outp = wmt;  K = 256; N = 256; int q = bid - 24; kt = q >> 2; nt = q & 3; }
    else               { in = wo;  outp = wot;  K = 512; N = 256; int q = bid - 40; kt = q >> 2; nt = q & 3; }
    __shared__ u16 T[64][66];
    int c = t & 63, r0 = t >> 6;
#pragma unroll
    for (int i = 0; i < 16; i++) {
        int r = r0 + i * 4;
        T[r][c] = f2b(in[(size_t)(kt * 64 + r) * N + nt * 64 + c]);  // coalesced
    }
    __syncthreads();
#pragma unroll
    for (int i = 0; i < 16; i++) {
        int r = r0 + i * 4;  // output row (n-dim)
        outp[(size_t)(nt * 64 + r) * K + kt * 64 + c] = T[c][r];     // coalesced
    }
}

// ---------------------------------------------------------------------------
// K1: exact KNN k=16, stable (d, idx)-lexicographic == jax.lax.top_k(-dist).
// ---------------------------------------------------------------------------
__global__ __launch_bounds__(256) void knn_kernel(const float* __restrict__ centers,
                                                  int* __restrict__ knn) {
    __shared__ float cx[NPT], cy[NPT], cz[NPT], sq[NPT];
    __shared__ float dl[4][64][17];
    __shared__ int il[4][64][17];
    int blk = blockIdx.x;
    int b = blk >> 2, n0 = (blk & 3) * 64;
    int h = threadIdx.x;
    int s = h >> 6, pt = h & 63;
    {
        const float* cb = centers + (size_t)b * NPT * 3;
        float x = cb[h * 3 + 0], y = cb[h * 3 + 1], z = cb[h * 3 + 2];
        cx[h] = x; cy[h] = y; cz[h] = z;
        sq[h] = x * x + y * y + z * z;
    }
    __syncthreads();
    int n = n0 + pt;
    float x = cx[n], y = cy[n], z = cz[n], sn = sq[n];
    float bd[KNN];
    int bi[KNN];
#pragma unroll
    for (int j = 0; j < KNN; j++) { bd[j] = 1e30f; bi[j] = 0x7fffffff; }
    for (int mm = 0; mm < 64; mm++) {
        int m = s * 64 + mm;
        float dot = x * cx[m] + y * cy[m] + z * cz[m];
        float d2 = (sn + sq[m]) - 2.0f * dot;
        float d = sqrtf(fmaxf(d2, 0.0f));
        if (d < bd[KNN - 1]) {  // in-order scan + strict < == lexicographic
            bd[KNN - 1] = d; bi[KNN - 1] = m;
#pragma unroll
            for (int p = KNN - 1; p > 0; --p) {
                if (bd[p - 1] > bd[p]) {
                    float td = bd[p - 1]; bd[p - 1] = bd[p]; bd[p] = td;
                    int ti = bi[p - 1]; bi[p - 1] = bi[p]; bi[p] = ti;
                }
            }
        }
    }
#pragma unroll
    for (int j = 0; j < KNN; j++) { dl[s][pt][j] = bd[j]; il[s][pt][j] = bi[j]; }
    __syncthreads();
    if (s == 0) {
        float md[KNN];
        int mi[KNN];
#pragma unroll
        for (int j = 0; j < KNN; j++) { md[j] = dl[0][pt][j]; mi[j] = il[0][pt][j]; }
        for (int t = 1; t < 4; t++) {
            for (int j = 0; j < KNN; j++) {
                float d = dl[t][pt][j];
                int idx = il[t][pt][j];
                bool ins = (d < md[KNN - 1]) || (d == md[KNN - 1] && idx < mi[KNN - 1]);
                if (!ins) break;  // source list sorted lexicographically
                md[KNN - 1] = d; mi[KNN - 1] = idx;
#pragma unroll
                for (int p = KNN - 1; p > 0; --p) {
                    bool sw = (md[p - 1] > md[p]) ||
                              (md[p - 1] == md[p] && mi[p - 1] > mi[p]);
                    if (sw) {
                        float td = md[p - 1]; md[p - 1] = md[p]; md[p] = td;
                        int ti = mi[p - 1]; mi[p - 1] = mi[p]; mi[p] = ti;
                    }
                }
            }
        }
        int* kp = knn + (b * NPT + n0 + pt) * KNN;
#pragma unroll
        for (int j = 0; j < KNN; j++) kp[j] = mi[j];
    }
}

// ---------------------------------------------------------------------------
// K2: text gate / bias per batch. 1024 threads, dot split 2-way + LDS reduce.
// ---------------------------------------------------------------------------
__global__ __launch_bounds__(1024) void gate_kernel(const float* __restrict__ tg_g,
                                                    const float* __restrict__ wg,
                                                    const float* __restrict__ bg,
                                                    const float* __restrict__ wtb,
                                                    const float* __restrict__ btb,
                                                    float* __restrict__ gate,
                                                    float* __restrict__ tbias) {
    __shared__ float tg[H];
    __shared__ float red[1024];
    int b = blockIdx.x, t = threadIdx.x;
    if (t < H) tg[t] = tg_g[b * H + t];
    __syncthreads();
    int o = t & 511;        // 512 outputs: 0..255 gate, 256..511 tbias
    int half = t >> 9;      // 0 or 1: which half of the K range
    int h = o & 255;
    const float* wsel = (o < 256) ? wg : wtb;
    float a = 0.0f;
#pragma unroll 4
    for (int i = half * 128; i < half * 128 + 128; i++)
        a += tg[i] * wsel[i * H + h];
    red[t] = a;
    __syncthreads();
    if (t < 512) {
        float s = red[t] + red[t + 512];
        if (o < 256) {
            gate[b * H + h] = 1.0f / (1.0f + expf(-(s + bg[h])));
        } else {
            tbias[b * H + h] = s + btb[h];
        }
    }
}

// ---------------------------------------------------------------------------
// K3: MSGB = bf16(relu(feat @ Wm + bm)), MFMA. R16: 32 points/block
// (512 blocks, 2/CU — was 1/CU; staging latency now has a partner block).
// ---------------------------------------------------------------------------
__global__ __launch_bounds__(256, 4) void msg_mfma(const float* __restrict__ feat,
                                                   const u16* __restrict__ wmt,
                                                   const float* __restrict__ bm,
                                                   u16* __restrict__ MSGB) {
    __shared__ __attribute__((aligned(16))) u16 A[32][264];
    int p0 = blockIdx.x * 32, h = threadIdx.x;
    int w = h >> 6, lane = h & 63, quad = lane >> 4, lq = lane & 15;
#pragma unroll 8
    for (int row = 0; row < 32; row++)
        A[row][h] = f2b(feat[(size_t)(p0 + row) * H + h]);
    __syncthreads();
    floatx4 acc[2][4];
#pragma unroll
    for (int rt = 0; rt < 2; rt++)
#pragma unroll
        for (int ct = 0; ct < 4; ct++) acc[rt][ct] = (floatx4){0, 0, 0, 0};
#pragma unroll 2
    for (int kt = 0; kt < 8; kt++) {
        shortx8 bf[4];
#pragma unroll
        for (int ct = 0; ct < 4; ct++)
            bf[ct] = *(const shortx8*)&wmt[(w * 64 + ct * 16 + lq) * 256 + kt * 32 + quad * 8];
#pragma unroll
        for (int rt = 0; rt < 2; rt++) {
            shortx8 a = *(const shortx8*)&A[rt * 16 + lq][kt * 32 + quad * 8];
#pragma unroll
            for (int ct = 0; ct < 4; ct++)
                acc[rt][ct] = __builtin_amdgcn_mfma_f32_16x16x32_bf16(a, bf[ct], acc[rt][ct], 0, 0, 0);
        }
    }
#pragma unroll
    for (int ct = 0; ct < 4; ct++) {
        int col = w * 64 + ct * 16 + lq;
        float bmc = bm[col];
#pragma unroll
        for (int rt = 0; rt < 2; rt++)
#pragma unroll
            for (int r = 0; r < 4; r++) {
                int row = rt * 16 + quad * 4 + r;
                MSGB[(size_t)(p0 + row) * H + col] = f2b(fmaxf(acc[rt][ct][r] + bmc, 0.0f));
            }
    }
}

// ---------------------------------------------------------------------------
// K4: fused edge pipeline, 4 points/block (M=64 edges). R10 structure,
// R14 epilogue reorder, R15 f32 feat gathers + setprio. UNCHANGED from R15.
// ---------------------------------------------------------------------------
__global__ __launch_bounds__(256, 4) void edge_mfma(
    const float* __restrict__ feat,
    const float* __restrict__ centers,
    const u16* __restrict__ w1t,
    const u16* __restrict__ w2t, const float* __restrict__ b2v,
    const u16* __restrict__ we1t, const float* __restrict__ be1,
    const float* __restrict__ we2, const float* __restrict__ be2,
    const int* __restrict__ knn, const float* __restrict__ gateG,
    const float* __restrict__ tbiasG, const u16* __restrict__ MSGB,
    u16* __restrict__ ctxB) {
    __shared__ __attribute__((aligned(16))) u16 A[64][264];  // g1 then edge_feat
    __shared__ float fnS[4][H];
    __shared__ __attribute__((aligned(16))) float geomS[64][4];
    __shared__ int nidxS[64];
    __shared__ float part[4][64];
    __shared__ float logitsS[64];
    __shared__ float alphaS[64];

    int bn0 = blockIdx.x * 4;
    int b = bn0 >> 8, n0 = bn0 & 255;
    int h = threadIdx.x;
    int w = h >> 6, lane = h & 63, quad = lane >> 4, lq = lane & 15;

    // phase 0: nidx + fn staging
    if (h < 64) nidxS[h] = knn[bn0 * KNN + h];
#pragma unroll
    for (int p = 0; p < 4; p++)
        fnS[p][h] = feat[(size_t)(bn0 + p) * H + h];
    // phase 1: geom per edge-row (h<64: point p=h>>4, neighbor j=h&15);
    // reads only own-thread nidxS[h] write from phase 0.
    if (h < 64) {
        int p = h >> 4;
        int m = nidxS[h];
        int n = n0 + p;
        const float* cb = centers + (size_t)b * NPT * 3;
        float rx = cb[m * 3 + 0] - cb[n * 3 + 0];
        float ry = cb[m * 3 + 1] - cb[n * 3 + 1];
        float rz = cb[m * 3 + 2] - cb[n * 3 + 2];
        float dist = sqrtf(rx * rx + ry * ry + rz * rz) + 1e-6f;
        geomS[h][0] = rx; geomS[h][1] = ry; geomS[h][2] = rz;
        geomS[h][3] = log1pf(dist);
    }
    __syncthreads();

    // phase 2: g1[64][256] = relu(geomP @ W1t) via MFMA (K=32 padded, k=4 bias)
    {
        shortx8 bw1[4];
#pragma unroll
        for (int ct = 0; ct < 4; ct++)
            bw1[ct] = *(const shortx8*)&w1t[(w * 64 + ct * 16 + lq) * 32 + quad * 8];
#pragma unroll
        for (int rt = 0; rt < 4; rt++) {
            shortx8 ag = {0, 0, 0, 0, 0, 0, 0, 0};
            if (quad == 0) {
                float4 g = *(const float4*)&geomS[rt * 16 + lq][0];
                ag[0] = (short)f2b(g.x);
                ag[1] = (short)f2b(g.y);
                ag[2] = (short)f2b(g.z);
                ag[3] = (short)f2b(g.w);
                ag[4] = (short)0x3F80;  // 1.0 -> multiplies bias row of w1t
            }
#pragma unroll
            for (int ct = 0; ct < 4; ct++) {
                floatx4 accg = __builtin_amdgcn_mfma_f32_16x16x32_bf16(
                    ag, bw1[ct], (floatx4){0, 0, 0, 0}, 0, 0, 0);
#pragma unroll
                for (int r = 0; r < 4; r++)
                    A[rt * 16 + quad * 4 + r][w * 64 + ct * 16 + lq] =
                        f2b(fmaxf(accg[r], 0.0f));
            }
        }
    }
    __syncthreads();

    // GEMM1: C1[64][256] = g1 @ W2
    floatx4 acc[4][4];
#pragma unroll
    for (int rt = 0; rt < 4; rt++)
#pragma unroll
        for (int ct = 0; ct < 4; ct++) acc[rt][ct] = (floatx4){0, 0, 0, 0};
    __builtin_amdgcn_s_setprio(1);
#pragma unroll 2
    for (int kt = 0; kt < 8; kt++) {
        shortx8 bf[4];
#pragma unroll
        for (int ct = 0; ct < 4; ct++)
            bf[ct] = *(const shortx8*)&w2t[(w * 64 + ct * 16 + lq) * 256 + kt * 32 + quad * 8];
#pragma unroll
        for (int rt = 0; rt < 4; rt++) {
            shortx8 a = *(const shortx8*)&A[rt * 16 + lq][kt * 32 + quad * 8];
#pragma unroll
            for (int ct = 0; ct < 4; ct++)
                acc[rt][ct] = __builtin_amdgcn_mfma_f32_16x16x32_bf16(a, bf[ct], acc[rt][ct], 0, 0, 0);
        }
    }
    __builtin_amdgcn_s_setprio(0);
    __syncthreads();  // all g1 reads done

    // epilogue1: edge_feat = tanh(fn + fb + relu(C1+b2)*gate + tbias) -> A
    // R14 order: (rt,r) outer / ct inner; row base once; col scalars hoisted.
    // R15: fb gathered from feat f32 directly.
    {
        float b2c4[4], gc4[4], tc4[4];
#pragma unroll
        for (int ct = 0; ct < 4; ct++) {
            int col = w * 64 + ct * 16 + lq;
            b2c4[ct] = b2v[col];
            gc4[ct]  = gateG[b * H + col];
            tc4[ct]  = tbiasG[b * H + col];
        }
#pragma unroll
        for (int rt = 0; rt < 4; rt++) {
            float fnt4[4];
#pragma unroll
            for (int ct = 0; ct < 4; ct++)
                fnt4[ct] = fnS[rt][w * 64 + ct * 16 + lq] + tc4[ct];
#pragma unroll
            for (int r = 0; r < 4; r++) {
                int row = rt * 16 + quad * 4 + r;
                const float* rowp = feat + ((size_t)b * NPT + nidxS[row]) * H + w * 64 + lq;
#pragma unroll
                for (int ct = 0; ct < 4; ct++) {
                    float fb = rowp[ct * 16];
                    float emb = fmaxf(acc[rt][ct][r] + b2c4[ct], 0.0f);
                    A[row][w * 64 + ct * 16 + lq] = f2b(fast_tanh(fnt4[ct] + fb + emb * gc4[ct]));
                }
            }
        }
    }
    __syncthreads();

    // GEMM2: C2[64][128] = edge_feat @ We1
    floatx4 acc2[4][2];
#pragma unroll
    for (int rt = 0; rt < 4; rt++)
#pragma unroll
        for (int c2 = 0; c2 < 2; c2++) acc2[rt][c2] = (floatx4){0, 0, 0, 0};
    __builtin_amdgcn_s_setprio(1);
#pragma unroll 2
    for (int kt = 0; kt < 8; kt++) {
        shortx8 bf[2];
#pragma unroll
        for (int c2 = 0; c2 < 2; c2++)
            bf[c2] = *(const shortx8*)&we1t[(w * 32 + c2 * 16 + lq) * 256 + kt * 32 + quad * 8];
#pragma unroll
        for (int rt = 0; rt < 4; rt++) {
            shortx8 a = *(const shortx8*)&A[rt * 16 + lq][kt * 32 + quad * 8];
#pragma unroll
            for (int c2 = 0; c2 < 2; c2++)
                acc2[rt][c2] = __builtin_amdgcn_mfma_f32_16x16x32_bf16(a, bf[c2], acc2[rt][c2], 0, 0, 0);
        }
    }
    __builtin_amdgcn_s_setprio(0);

    // logits partials
    float pl[4][4];
#pragma unroll
    for (int rt = 0; rt < 4; rt++)
#pragma unroll
        for (int r = 0; r < 4; r++) pl[rt][r] = 0.0f;
#pragma unroll
    for (int c2 = 0; c2 < 2; c2++) {
        int col = w * 32 + c2 * 16 + lq;
        float be1c = be1[col], w2c = we2[col];
#pragma unroll
        for (int rt = 0; rt < 4; rt++)
#pragma unroll
            for (int r = 0; r < 4; r++)
                pl[rt][r] += fmaxf(acc2[rt][c2][r] + be1c, 0.0f) * w2c;
    }
#pragma unroll
    for (int d = 1; d < 16; d <<= 1)
#pragma unroll
        for (int rt = 0; rt < 4; rt++)
#pragma unroll
            for (int r = 0; r < 4; r++) pl[rt][r] += __shfl_xor(pl[rt][r], d, 16);
    if (lq == 0) {
#pragma unroll
        for (int rt = 0; rt < 4; rt++)
#pragma unroll
            for (int r = 0; r < 4; r++)
                part[w][rt * 16 + quad * 4 + r] = pl[rt][r];
    }
    __syncthreads();
    if (h < 64)
        logitsS[h] = part[0][h] + part[1][h] + part[2][h] + part[3][h] + be2[0];
    __syncthreads();
    if (h < 64) {
        int base = (h >> 4) * 16;
        float mx = -1e30f;
#pragma unroll
        for (int j = 0; j < KNN; j++) mx = fmaxf(mx, logitsS[base + j]);
        float sum = 0.0f;
#pragma unroll
        for (int j = 0; j < KNN; j++) sum += expf(logitsS[base + j] - mx);
        alphaS[h] = expf(logitsS[h] - mx) / sum;
    }
    __syncthreads();

    // ctx: thread -> (point p, 4 cols); bf16 gather over 16 nbrs, bf16 write
    {
        int p = h >> 6, cg = (h & 63) * 4;
        float4 c = {0, 0, 0, 0};
#pragma unroll
        for (int j = 0; j < KNN; j++) {
            float al = alphaS[p * 16 + j];
            const u32* mp = (const u32*)&MSGB[((size_t)b * NPT + nidxS[p * 16 + j]) * H + cg];
            u32 m0 = mp[0], m1 = mp[1];
            c.x += al * __uint_as_float(m0 << 16);
            c.y += al * __uint_as_float(m0 & 0xFFFF0000u);
            c.z += al * __uint_as_float(m1 << 16);
            c.w += al * __uint_as_float(m1 & 0xFFFF0000u);
        }
        uint2 st;
        st.x = (u32)f2b(c.x) | ((u32)f2b(c.y) << 16);
        st.y = (u32)f2b(c.z) | ((u32)f2b(c.w) << 16);
        *(uint2*)&ctxB[(size_t)(bn0 + p) * H + cg] = st;
    }
}

// ---------------------------------------------------------------------------
// K5: out = LN(feat + relu([feat|ctx] @ Wo + bo)), MFMA. R16: 16 points/
// block (1024 blocks, 4/CU — was 2/CU).
// ---------------------------------------------------------------------------
__global__ __launch_bounds__(256, 4) void out_mfma(const float* __restrict__ feat,
                                                   const u16* __restrict__ ctxB,
                                                   const u16* __restrict__ wot,
                                                   const float* __restrict__ bo,
                                                   const float* __restrict__ gamma,
                                                   const float* __restrict__ beta,
                                                   float* __restrict__ out) {
    __shared__ __attribute__((aligned(16))) u16 A[16][520];
    __shared__ float redS[4][16], redS2[4][16];
    int p0 = blockIdx.x * 16, h = threadIdx.x;
    int w = h >> 6, lane = h & 63, quad = lane >> 4, lq = lane & 15;
#pragma unroll 8
    for (int row = 0; row < 16; row++) {
        A[row][h]       = f2b(feat[(size_t)(p0 + row) * H + h]);
        A[row][256 + h] = ctxB[(size_t)(p0 + row) * H + h];
    }
    __syncthreads();
    floatx4 acc[4];
#pragma unroll
    for (int ct = 0; ct < 4; ct++) acc[ct] = (floatx4){0, 0, 0, 0};
#pragma unroll 2
    for (int kt = 0; kt < 16; kt++) {
        shortx8 a = *(const shortx8*)&A[lq][kt * 32 + quad * 8];
#pragma unroll
        for (int ct = 0; ct < 4; ct++) {
            shortx8 bf = *(const shortx8*)&wot[(w * 64 + ct * 16 + lq) * 512 + kt * 32 + quad * 8];
            acc[ct] = __builtin_amdgcn_mfma_f32_16x16x32_bf16(a, bf, acc[ct], 0, 0, 0);
        }
    }
    float x[4][4];
    float sm[4], sq2[4];
#pragma unroll
    for (int r = 0; r < 4; r++) { sm[r] = 0.0f; sq2[r] = 0.0f; }
#pragma unroll
    for (int ct = 0; ct < 4; ct++) {
        int col = w * 64 + ct * 16 + lq;
        float boc = bo[col];
#pragma unroll
        for (int r = 0; r < 4; r++) {
            int row = quad * 4 + r;
            float xx = feat[(size_t)(p0 + row) * H + col] +
                       fmaxf(acc[ct][r] + boc, 0.0f);
            x[ct][r] = xx;
            sm[r] += xx;
            sq2[r] += xx * xx;
        }
    }
#pragma unroll
    for (int d = 1; d < 16; d <<= 1)
#pragma unroll
        for (int r = 0; r < 4; r++) {
            sm[r] += __shfl_xor(sm[r], d, 16);
            sq2[r] += __shfl_xor(sq2[r], d, 16);
        }
    if (lq == 0) {
#pragma unroll
        for (int r = 0; r < 4; r++) {
            redS[w][quad * 4 + r] = sm[r];
            redS2[w][quad * 4 + r] = sq2[r];
        }
    }
    __syncthreads();
#pragma unroll
    for (int r = 0; r < 4; r++) {
        int row = quad * 4 + r;
        float s1 = redS[0][row] + redS[1][row] + redS[2][row] + redS[3][row];
        float s2 = redS2[0][row] + redS2[1][row] + redS2[2][row] + redS2[3][row];
        float mu = s1 * (1.0f / H);
        float var = s2 * (1.0f / H) - mu * mu;
        float inv = rsqrtf(fmaxf(var, 0.0f) + 1e-5f);
#pragma unroll
        for (int ct = 0; ct < 4; ct++) {
            int col = w * 64 + ct * 16 + lq;
            out[(size_t)(p0 + row) * H + col] =
                (x[ct][r] - mu) * inv * gamma[col] + beta[col];
        }
    }
}

// ---------------------------------------------------------------------------
extern "C" void kernel_launch(void* const* d_in, const int* in_sizes, int n_in,
                              void* d_out, int out_size, void* d_ws, size_t ws_size,
                              hipStream_t stream) {
    const float* feat    = (const float*)d_in[0];
    const float* centers = (const float*)d_in[1];
    const float* textg   = (const float*)d_in[2];
    const float* w1      = (const float*)d_in[3];
    const float* b1      = (const float*)d_in[4];
    const float* w2      = (const float*)d_in[5];
    const float* b2      = (const float*)d_in[6];
    const float* wg      = (const float*)d_in[7];
    const float* bg      = (const float*)d_in[8];
    const float* wtb     = (const float*)d_in[9];
    const float* btb     = (const float*)d_in[10];
    const float* we1     = (const float*)d_in[11];
    const float* be1     = (const float*)d_in[12];
    const float* we2     = (const float*)d_in[13];
    const float* be2     = (const float*)d_in[14];
    const float* wm      = (const float*)d_in[15];
    const float* bm      = (const float*)d_in[16];
    const float* wo      = (const float*)d_in[17];
    const float* bo      = (const float*)d_in[18];
    const float* gamma   = (const float*)d_in[19];
    const float* beta    = (const float*)d_in[20];

    char* ws = (char*)d_ws;
    size_t off = 0;
    int* knn     = (int*)(ws + off);   off += (size_t)BB * NPT * KNN * 4;   // 1 MB
    float* gate  = (float*)(ws + off); off += (size_t)BB * H * 4;           // 64 KB
    float* tbias = (float*)(ws + off); off += (size_t)BB * H * 4;           // 64 KB
    u16* MSGB    = (u16*)(ws + off);   off += (size_t)BB * NPT * H * 2;     // 8 MB
    u16* ctxB    = (u16*)(ws + off);   off += (size_t)BB * NPT * H * 2;     // 8 MB
    u16* w2t     = (u16*)(ws + off);   off += (size_t)256 * 256 * 2;        // 128 KB
    u16* we1t    = (u16*)(ws + off);   off += (size_t)128 * 256 * 2;        // 64 KB
    u16* wmt     = (u16*)(ws + off);   off += (size_t)256 * 256 * 2;        // 128 KB
    u16* wot     = (u16*)(ws + off);   off += (size_t)256 * 512 * 2;        // 256 KB
    u16* w1t     = (u16*)(ws + off);   off += (size_t)256 * 32 * 2;         // 16 KB

    prep_kernel<<<73, 256, 0, stream>>>(w2, we1, wm, wo, w1, b1,
                                        w2t, we1t, wmt, wot, w1t);
    knn_kernel<<<256, 256, 0, stream>>>(centers, knn);
    gate_kernel<<<BB, 1024, 0, stream>>>(textg, wg, bg, wtb, btb, gate, tbias);
    msg_mfma<<<BB * NPT / 32, 256, 0, stream>>>(feat, wmt, bm, MSGB);
    edge_mfma<<<BB * NPT / 4, 256, 0, stream>>>(feat, centers, w1t, w2t, b2,
                                                we1t, be1, we2, be2, knn, gate, tbias,
                                                MSGB, ctxB);
    out_mfma<<<BB * NPT / 16, 256, 0, stream>>>(feat, ctxB, wot, bo,
                                                gamma, beta, (float*)d_out);
}

// Round 6
// 342.009 us; speedup vs baseline: 1.0418x; 1.0418x over previous
//
#include <hip/hip_runtime.h>
#include <hip/hip_bf16.h>

#define H 256
#define KNN 16
#define NPT 256
#define BB 64

typedef unsigned short u16;
typedef unsigned int u32;
typedef __attribute__((ext_vector_type(8))) short shortx8;
typedef __attribute__((ext_vector_type(4))) float floatx4;

// RNE f32->bf16 via hw cvt; same rounding as manual (u + 0x7fff + lsb) >> 16.
__device__ __forceinline__ u16 f2b(float f) {
    return __builtin_bit_cast(u16, __float2bfloat16(f));
}
__device__ __forceinline__ float b2f(u16 u) {
    return __uint_as_float(((u32)u) << 16);
}

// tanh via hw exp2: 1 - 2/(exp2(x*2log2e)+1). |err| ~1e-6, saturates correctly.
__device__ __forceinline__ float fast_tanh(float x) {
    float e = __builtin_amdgcn_exp2f(x * 2.88539008177793f);
    return 1.0f - 2.0f * __builtin_amdgcn_rcpf(e + 1.0f);
}

// ---------------------------------------------------------------------------
// Session ledger:
// R10: edge M=64 interleaved gathers 146us PROVEN. R11: reg prefetch spills
//      (+75). R12: global_load_lds staging serializes (+4). R13: edge M=32
//      halved -> per-block weight re-stream dominates (+92): NEVER shrink a
//      tile that streams weights. R14: epilogue reorder 146->138. R15:
//      featB removed: total -2 only -> reset cost not ~ ws bytes; setprio
//      null. R16: msg/out tile-halving repeated the R13 mistake (+20us,
//      reverted here); prep tiled-transpose kept (neutral-to-good).
// DISPATCH-ID FACT: ~64 dispatches/iter, 6 ours -> ~200us stable harness
//      floor (poison/reset). Controllable time = edge (137) + small (~45).
// R17: edge FETCH=88MB vs ~35MB ideal -> gathers L2-thrash (every XCD
//      touches all 64 batches, 32MB >> 4MB L2). Bijective batch-locality
//      swizzle: wid=(bid&7)*512+(bid>>3) -> XCD x owns batches [8x,8x+8),
//      ~3MB/XCD L2-resident. Gathers become L2 hits (~200cy vs ~900cy).
// ---------------------------------------------------------------------------
// K0: prep — LDS 64x64 tiled transpose, coalesced both sides, [64][66] u16
// pad = conflict-free transposed read. Blocks 0..71 = tiles of
// {w2,we1,wm,wo}; block 72 = w1t special (tiny).
// ---------------------------------------------------------------------------
__global__ __launch_bounds__(256) void prep_kernel(
    const float* __restrict__ w2, const float* __restrict__ we1,
    const float* __restrict__ wm, const float* __restrict__ wo,
    const float* __restrict__ w1, const float* __restrict__ b1,
    u16* __restrict__ w2t, u16* __restrict__ we1t,
    u16* __restrict__ wmt, u16* __restrict__ wot, u16* __restrict__ w1t) {
    int bid = blockIdx.x, t = threadIdx.x;
    if (bid == 72) {  // w1t: 256 x 32, k<4 from w1, k==4 bias row, else 0
        for (int e = t; e < 8192; e += 256) {
            int n = e >> 5, k = e & 31;
            float v = (k < 4) ? w1[k * 256 + n] : (k == 4 ? b1[n] : 0.0f);
            w1t[e] = f2b(v);
        }
        return;
    }
    const float* in; u16* outp; int K, N, kt, nt;
    if (bid < 16)      { in = w2;  outp = w2t;  K = 256; N = 256; int q = bid;      kt = q >> 2; nt = q & 3; }
    else if (bid < 24) { in = we1; outp = we1t; K = 256; N = 128; int q = bid - 16; kt = q >> 1; nt = q & 1; }
    else if (bid < 40) { in = wm;  outp = wmt;  K = 256; N = 256; int q = bid - 24; kt = q >> 2; nt = q & 3; }
    else               { in = wo;  outp = wot;  K = 512; N = 256; int q = bid - 40; kt = q >> 2; nt = q & 3; }
    __shared__ u16 T[64][66];
    int c = t & 63, r0 = t >> 6;
#pragma unroll
    for (int i = 0; i < 16; i++) {
        int r = r0 + i * 4;
        T[r][c] = f2b(in[(size_t)(kt * 64 + r) * N + nt * 64 + c]);  // coalesced
    }
    __syncthreads();
#pragma unroll
    for (int i = 0; i < 16; i++) {
        int r = r0 + i * 4;  // output row (n-dim)
        outp[(size_t)(nt * 64 + r) * K + kt * 64 + c] = T[c][r];     // coalesced
    }
}

// ---------------------------------------------------------------------------
// K1: exact KNN k=16, stable (d, idx)-lexicographic == jax.lax.top_k(-dist).
// ---------------------------------------------------------------------------
__global__ __launch_bounds__(256) void knn_kernel(const float* __restrict__ centers,
                                                  int* __restrict__ knn) {
    __shared__ float cx[NPT], cy[NPT], cz[NPT], sq[NPT];
    __shared__ float dl[4][64][17];
    __shared__ int il[4][64][17];
    int blk = blockIdx.x;
    int b = blk >> 2, n0 = (blk & 3) * 64;
    int h = threadIdx.x;
    int s = h >> 6, pt = h & 63;
    {
        const float* cb = centers + (size_t)b * NPT * 3;
        float x = cb[h * 3 + 0], y = cb[h * 3 + 1], z = cb[h * 3 + 2];
        cx[h] = x; cy[h] = y; cz[h] = z;
        sq[h] = x * x + y * y + z * z;
    }
    __syncthreads();
    int n = n0 + pt;
    float x = cx[n], y = cy[n], z = cz[n], sn = sq[n];
    float bd[KNN];
    int bi[KNN];
#pragma unroll
    for (int j = 0; j < KNN; j++) { bd[j] = 1e30f; bi[j] = 0x7fffffff; }
    for (int mm = 0; mm < 64; mm++) {
        int m = s * 64 + mm;
        float dot = x * cx[m] + y * cy[m] + z * cz[m];
        float d2 = (sn + sq[m]) - 2.0f * dot;
        float d = sqrtf(fmaxf(d2, 0.0f));
        if (d < bd[KNN - 1]) {  // in-order scan + strict < == lexicographic
            bd[KNN - 1] = d; bi[KNN - 1] = m;
#pragma unroll
            for (int p = KNN - 1; p > 0; --p) {
                if (bd[p - 1] > bd[p]) {
                    float td = bd[p - 1]; bd[p - 1] = bd[p]; bd[p] = td;
                    int ti = bi[p - 1]; bi[p - 1] = bi[p]; bi[p] = ti;
                }
            }
        }
    }
#pragma unroll
    for (int j = 0; j < KNN; j++) { dl[s][pt][j] = bd[j]; il[s][pt][j] = bi[j]; }
    __syncthreads();
    if (s == 0) {
        float md[KNN];
        int mi[KNN];
#pragma unroll
        for (int j = 0; j < KNN; j++) { md[j] = dl[0][pt][j]; mi[j] = il[0][pt][j]; }
        for (int t = 1; t < 4; t++) {
            for (int j = 0; j < KNN; j++) {
                float d = dl[t][pt][j];
                int idx = il[t][pt][j];
                bool ins = (d < md[KNN - 1]) || (d == md[KNN - 1] && idx < mi[KNN - 1]);
                if (!ins) break;  // source list sorted lexicographically
                md[KNN - 1] = d; mi[KNN - 1] = idx;
#pragma unroll
                for (int p = KNN - 1; p > 0; --p) {
                    bool sw = (md[p - 1] > md[p]) ||
                              (md[p - 1] == md[p] && mi[p - 1] > mi[p]);
                    if (sw) {
                        float td = md[p - 1]; md[p - 1] = md[p]; md[p] = td;
                        int ti = mi[p - 1]; mi[p - 1] = mi[p]; mi[p] = ti;
                    }
                }
            }
        }
        int* kp = knn + (b * NPT + n0 + pt) * KNN;
#pragma unroll
        for (int j = 0; j < KNN; j++) kp[j] = mi[j];
    }
}

// ---------------------------------------------------------------------------
// K2: text gate / bias per batch. 1024 threads, dot split 2-way + LDS reduce.
// ---------------------------------------------------------------------------
__global__ __launch_bounds__(1024) void gate_kernel(const float* __restrict__ tg_g,
                                                    const float* __restrict__ wg,
                                                    const float* __restrict__ bg,
                                                    const float* __restrict__ wtb,
                                                    const float* __restrict__ btb,
                                                    float* __restrict__ gate,
                                                    float* __restrict__ tbias) {
    __shared__ float tg[H];
    __shared__ float red[1024];
    int b = blockIdx.x, t = threadIdx.x;
    if (t < H) tg[t] = tg_g[b * H + t];
    __syncthreads();
    int o = t & 511;        // 512 outputs: 0..255 gate, 256..511 tbias
    int half = t >> 9;      // 0 or 1: which half of the K range
    int h = o & 255;
    const float* wsel = (o < 256) ? wg : wtb;
    float a = 0.0f;
#pragma unroll 4
    for (int i = half * 128; i < half * 128 + 128; i++)
        a += tg[i] * wsel[i * H + h];
    red[t] = a;
    __syncthreads();
    if (t < 512) {
        float s = red[t] + red[t + 512];
        if (o < 256) {
            gate[b * H + h] = 1.0f / (1.0f + expf(-(s + bg[h])));
        } else {
            tbias[b * H + h] = s + btb[h];
        }
    }
}

// ---------------------------------------------------------------------------
// K3: MSGB = bf16(relu(feat @ Wm + bm)), MFMA, 64 points/block (R15 config —
// R16's 32pt halving doubled wmt re-streaming, reverted).
// ---------------------------------------------------------------------------
__global__ __launch_bounds__(256, 4) void msg_mfma(const float* __restrict__ feat,
                                                   const u16* __restrict__ wmt,
                                                   const float* __restrict__ bm,
                                                   u16* __restrict__ MSGB) {
    __shared__ __attribute__((aligned(16))) u16 A[64][264];
    int p0 = blockIdx.x * 64, h = threadIdx.x;
    int w = h >> 6, lane = h & 63, quad = lane >> 4, lq = lane & 15;
#pragma unroll 8
    for (int row = 0; row < 64; row++)
        A[row][h] = f2b(feat[(size_t)(p0 + row) * H + h]);
    __syncthreads();
    floatx4 acc[4][4];
#pragma unroll
    for (int rt = 0; rt < 4; rt++)
#pragma unroll
        for (int ct = 0; ct < 4; ct++) acc[rt][ct] = (floatx4){0, 0, 0, 0};
#pragma unroll 2
    for (int kt = 0; kt < 8; kt++) {
        shortx8 bf[4];
#pragma unroll
        for (int ct = 0; ct < 4; ct++)
            bf[ct] = *(const shortx8*)&wmt[(w * 64 + ct * 16 + lq) * 256 + kt * 32 + quad * 8];
#pragma unroll
        for (int rt = 0; rt < 4; rt++) {
            shortx8 a = *(const shortx8*)&A[rt * 16 + lq][kt * 32 + quad * 8];
#pragma unroll
            for (int ct = 0; ct < 4; ct++)
                acc[rt][ct] = __builtin_amdgcn_mfma_f32_16x16x32_bf16(a, bf[ct], acc[rt][ct], 0, 0, 0);
        }
    }
#pragma unroll
    for (int ct = 0; ct < 4; ct++) {
        int col = w * 64 + ct * 16 + lq;
        float bmc = bm[col];
#pragma unroll
        for (int rt = 0; rt < 4; rt++)
#pragma unroll
            for (int r = 0; r < 4; r++) {
                int row = rt * 16 + quad * 4 + r;
                MSGB[(size_t)(p0 + row) * H + col] = f2b(fmaxf(acc[rt][ct][r] + bmc, 0.0f));
            }
    }
}

// ---------------------------------------------------------------------------
// K4: fused edge pipeline, 4 points/block (M=64 edges). R10 structure,
// R14 epilogue reorder, R15 f32 gathers, R17 batch-locality XCD swizzle.
// ---------------------------------------------------------------------------
__global__ __launch_bounds__(256, 4) void edge_mfma(
    const float* __restrict__ feat,
    const float* __restrict__ centers,
    const u16* __restrict__ w1t,
    const u16* __restrict__ w2t, const float* __restrict__ b2v,
    const u16* __restrict__ we1t, const float* __restrict__ be1,
    const float* __restrict__ we2, const float* __restrict__ be2,
    const int* __restrict__ knn, const float* __restrict__ gateG,
    const float* __restrict__ tbiasG, const u16* __restrict__ MSGB,
    u16* __restrict__ ctxB) {
    __shared__ __attribute__((aligned(16))) u16 A[64][264];  // g1 then edge_feat
    __shared__ float fnS[4][H];
    __shared__ __attribute__((aligned(16))) float geomS[64][4];
    __shared__ int nidxS[64];
    __shared__ float part[4][64];
    __shared__ float logitsS[64];
    __shared__ float alphaS[64];

    // R17: bijective XCD swizzle (4096 blocks, 4096%8==0). Dispatch round-
    // robins blockIdx over 8 XCDs; remap so XCD x owns batches [8x, 8x+8)
    // -> per-XCD gather working set ~3MB, L2-resident.
    int wid = (blockIdx.x & 7) * 512 + (blockIdx.x >> 3);
    int bn0 = wid * 4;
    int b = bn0 >> 8, n0 = bn0 & 255;
    int h = threadIdx.x;
    int w = h >> 6, lane = h & 63, quad = lane >> 4, lq = lane & 15;

    // phase 0: nidx + fn staging
    if (h < 64) nidxS[h] = knn[bn0 * KNN + h];
#pragma unroll
    for (int p = 0; p < 4; p++)
        fnS[p][h] = feat[(size_t)(bn0 + p) * H + h];
    // phase 1: geom per edge-row (h<64: point p=h>>4, neighbor j=h&15);
    // reads only own-thread nidxS[h] write from phase 0.
    if (h < 64) {
        int p = h >> 4;
        int m = nidxS[h];
        int n = n0 + p;
        const float* cb = centers + (size_t)b * NPT * 3;
        float rx = cb[m * 3 + 0] - cb[n * 3 + 0];
        float ry = cb[m * 3 + 1] - cb[n * 3 + 1];
        float rz = cb[m * 3 + 2] - cb[n * 3 + 2];
        float dist = sqrtf(rx * rx + ry * ry + rz * rz) + 1e-6f;
        geomS[h][0] = rx; geomS[h][1] = ry; geomS[h][2] = rz;
        geomS[h][3] = log1pf(dist);
    }
    __syncthreads();

    // phase 2: g1[64][256] = relu(geomP @ W1t) via MFMA (K=32 padded, k=4 bias)
    {
        shortx8 bw1[4];
#pragma unroll
        for (int ct = 0; ct < 4; ct++)
            bw1[ct] = *(const shortx8*)&w1t[(w * 64 + ct * 16 + lq) * 32 + quad * 8];
#pragma unroll
        for (int rt = 0; rt < 4; rt++) {
            shortx8 ag = {0, 0, 0, 0, 0, 0, 0, 0};
            if (quad == 0) {
                float4 g = *(const float4*)&geomS[rt * 16 + lq][0];
                ag[0] = (short)f2b(g.x);
                ag[1] = (short)f2b(g.y);
                ag[2] = (short)f2b(g.z);
                ag[3] = (short)f2b(g.w);
                ag[4] = (short)0x3F80;  // 1.0 -> multiplies bias row of w1t
            }
#pragma unroll
            for (int ct = 0; ct < 4; ct++) {
                floatx4 accg = __builtin_amdgcn_mfma_f32_16x16x32_bf16(
                    ag, bw1[ct], (floatx4){0, 0, 0, 0}, 0, 0, 0);
#pragma unroll
                for (int r = 0; r < 4; r++)
                    A[rt * 16 + quad * 4 + r][w * 64 + ct * 16 + lq] =
                        f2b(fmaxf(accg[r], 0.0f));
            }
        }
    }
    __syncthreads();

    // GEMM1: C1[64][256] = g1 @ W2
    floatx4 acc[4][4];
#pragma unroll
    for (int rt = 0; rt < 4; rt++)
#pragma unroll
        for (int ct = 0; ct < 4; ct++) acc[rt][ct] = (floatx4){0, 0, 0, 0};
    __builtin_amdgcn_s_setprio(1);
#pragma unroll 2
    for (int kt = 0; kt < 8; kt++) {
        shortx8 bf[4];
#pragma unroll
        for (int ct = 0; ct < 4; ct++)
            bf[ct] = *(const shortx8*)&w2t[(w * 64 + ct * 16 + lq) * 256 + kt * 32 + quad * 8];
#pragma unroll
        for (int rt = 0; rt < 4; rt++) {
            shortx8 a = *(const shortx8*)&A[rt * 16 + lq][kt * 32 + quad * 8];
#pragma unroll
            for (int ct = 0; ct < 4; ct++)
                acc[rt][ct] = __builtin_amdgcn_mfma_f32_16x16x32_bf16(a, bf[ct], acc[rt][ct], 0, 0, 0);
        }
    }
    __builtin_amdgcn_s_setprio(0);
    __syncthreads();  // all g1 reads done

    // epilogue1: edge_feat = tanh(fn + fb + relu(C1+b2)*gate + tbias) -> A
    // R14 order: (rt,r) outer / ct inner; row base once; col scalars hoisted.
    {
        float b2c4[4], gc4[4], tc4[4];
#pragma unroll
        for (int ct = 0; ct < 4; ct++) {
            int col = w * 64 + ct * 16 + lq;
            b2c4[ct] = b2v[col];
            gc4[ct]  = gateG[b * H + col];
            tc4[ct]  = tbiasG[b * H + col];
        }
#pragma unroll
        for (int rt = 0; rt < 4; rt++) {
            float fnt4[4];
#pragma unroll
            for (int ct = 0; ct < 4; ct++)
                fnt4[ct] = fnS[rt][w * 64 + ct * 16 + lq] + tc4[ct];
#pragma unroll
            for (int r = 0; r < 4; r++) {
                int row = rt * 16 + quad * 4 + r;
                const float* rowp = feat + ((size_t)b * NPT + nidxS[row]) * H + w * 64 + lq;
#pragma unroll
                for (int ct = 0; ct < 4; ct++) {
                    float fb = rowp[ct * 16];
                    float emb = fmaxf(acc[rt][ct][r] + b2c4[ct], 0.0f);
                    A[row][w * 64 + ct * 16 + lq] = f2b(fast_tanh(fnt4[ct] + fb + emb * gc4[ct]));
                }
            }
        }
    }
    __syncthreads();

    // GEMM2: C2[64][128] = edge_feat @ We1
    floatx4 acc2[4][2];
#pragma unroll
    for (int rt = 0; rt < 4; rt++)
#pragma unroll
        for (int c2 = 0; c2 < 2; c2++) acc2[rt][c2] = (floatx4){0, 0, 0, 0};
    __builtin_amdgcn_s_setprio(1);
#pragma unroll 2
    for (int kt = 0; kt < 8; kt++) {
        shortx8 bf[2];
#pragma unroll
        for (int c2 = 0; c2 < 2; c2++)
            bf[c2] = *(const shortx8*)&we1t[(w * 32 + c2 * 16 + lq) * 256 + kt * 32 + quad * 8];
#pragma unroll
        for (int rt = 0; rt < 4; rt++) {
            shortx8 a = *(const shortx8*)&A[rt * 16 + lq][kt * 32 + quad * 8];
#pragma unroll
            for (int c2 = 0; c2 < 2; c2++)
                acc2[rt][c2] = __builtin_amdgcn_mfma_f32_16x16x32_bf16(a, bf[c2], acc2[rt][c2], 0, 0, 0);
        }
    }
    __builtin_amdgcn_s_setprio(0);

    // logits partials
    float pl[4][4];
#pragma unroll
    for (int rt = 0; rt < 4; rt++)
#pragma unroll
        for (int r = 0; r < 4; r++) pl[rt][r] = 0.0f;
#pragma unroll
    for (int c2 = 0; c2 < 2; c2++) {
        int col = w * 32 + c2 * 16 + lq;
        float be1c = be1[col], w2c = we2[col];
#pragma unroll
        for (int rt = 0; rt < 4; rt++)
#pragma unroll
            for (int r = 0; r < 4; r++)
                pl[rt][r] += fmaxf(acc2[rt][c2][r] + be1c, 0.0f) * w2c;
    }
#pragma unroll
    for (int d = 1; d < 16; d <<= 1)
#pragma unroll
        for (int rt = 0; rt < 4; rt++)
#pragma unroll
            for (int r = 0; r < 4; r++) pl[rt][r] += __shfl_xor(pl[rt][r], d, 16);
    if (lq == 0) {
#pragma unroll
        for (int rt = 0; rt < 4; rt++)
#pragma unroll
            for (int r = 0; r < 4; r++)
                part[w][rt * 16 + quad * 4 + r] = pl[rt][r];
    }
    __syncthreads();
    if (h < 64)
        logitsS[h] = part[0][h] + part[1][h] + part[2][h] + part[3][h] + be2[0];
    __syncthreads();
    if (h < 64) {
        int base = (h >> 4) * 16;
        float mx = -1e30f;
#pragma unroll
        for (int j = 0; j < KNN; j++) mx = fmaxf(mx, logitsS[base + j]);
        float sum = 0.0f;
#pragma unroll
        for (int j = 0; j < KNN; j++) sum += expf(logitsS[base + j] - mx);
        alphaS[h] = expf(logitsS[h] - mx) / sum;
    }
    __syncthreads();

    // ctx: thread -> (point p, 4 cols); bf16 gather over 16 nbrs, bf16 write
    {
        int p = h >> 6, cg = (h & 63) * 4;
        float4 c = {0, 0, 0, 0};
#pragma unroll
        for (int j = 0; j < KNN; j++) {
            float al = alphaS[p * 16 + j];
            const u32* mp = (const u32*)&MSGB[((size_t)b * NPT + nidxS[p * 16 + j]) * H + cg];
            u32 m0 = mp[0], m1 = mp[1];
            c.x += al * __uint_as_float(m0 << 16);
            c.y += al * __uint_as_float(m0 & 0xFFFF0000u);
            c.z += al * __uint_as_float(m1 << 16);
            c.w += al * __uint_as_float(m1 & 0xFFFF0000u);
        }
        uint2 st;
        st.x = (u32)f2b(c.x) | ((u32)f2b(c.y) << 16);
        st.y = (u32)f2b(c.z) | ((u32)f2b(c.w) << 16);
        *(uint2*)&ctxB[(size_t)(bn0 + p) * H + cg] = st;
    }
}

// ---------------------------------------------------------------------------
// K5: out = LN(feat + relu([feat|ctx] @ Wo + bo)), MFMA, 32 points/block
// (R15 config — R16's 16pt halving doubled wot re-streaming, reverted).
// ---------------------------------------------------------------------------
__global__ __launch_bounds__(256, 4) void out_mfma(const float* __restrict__ feat,
                                                   const u16* __restrict__ ctxB,
                                                   const u16* __restrict__ wot,
                                                   const float* __restrict__ bo,
                                                   const float* __restrict__ gamma,
                                                   const float* __restrict__ beta,
                                                   float* __restrict__ out) {
    __shared__ __attribute__((aligned(16))) u16 A[32][520];
    __shared__ float redS[4][32], redS2[4][32];
    int p0 = blockIdx.x * 32, h = threadIdx.x;
    int w = h >> 6, lane = h & 63, quad = lane >> 4, lq = lane & 15;
#pragma unroll 8
    for (int row = 0; row < 32; row++) {
        A[row][h]       = f2b(feat[(size_t)(p0 + row) * H + h]);
        A[row][256 + h] = ctxB[(size_t)(p0 + row) * H + h];
    }
    __syncthreads();
    floatx4 acc[2][4];
#pragma unroll
    for (int rt = 0; rt < 2; rt++)
#pragma unroll
        for (int ct = 0; ct < 4; ct++) acc[rt][ct] = (floatx4){0, 0, 0, 0};
#pragma unroll 2
    for (int kt = 0; kt < 16; kt++) {
        shortx8 bf[4];
#pragma unroll
        for (int ct = 0; ct < 4; ct++)
            bf[ct] = *(const shortx8*)&wot[(w * 64 + ct * 16 + lq) * 512 + kt * 32 + quad * 8];
#pragma unroll
        for (int rt = 0; rt < 2; rt++) {
            shortx8 a = *(const shortx8*)&A[rt * 16 + lq][kt * 32 + quad * 8];
#pragma unroll
            for (int ct = 0; ct < 4; ct++)
                acc[rt][ct] = __builtin_amdgcn_mfma_f32_16x16x32_bf16(a, bf[ct], acc[rt][ct], 0, 0, 0);
        }
    }
    float x[2][4][4];
    float sm[2][4], sq2[2][4];
#pragma unroll
    for (int rt = 0; rt < 2; rt++)
#pragma unroll
        for (int r = 0; r < 4; r++) { sm[rt][r] = 0.0f; sq2[rt][r] = 0.0f; }
#pragma unroll
    for (int rt = 0; rt < 2; rt++)
#pragma unroll
        for (int ct = 0; ct < 4; ct++) {
            int col = w * 64 + ct * 16 + lq;
            float boc = bo[col];
#pragma unroll
            for (int r = 0; r < 4; r++) {
                int row = rt * 16 + quad * 4 + r;
                float xx = feat[(size_t)(p0 + row) * H + col] +
                           fmaxf(acc[rt][ct][r] + boc, 0.0f);
                x[rt][ct][r] = xx;
                sm[rt][r] += xx;
                sq2[rt][r] += xx * xx;
            }
        }
#pragma unroll
    for (int d = 1; d < 16; d <<= 1)
#pragma unroll
        for (int rt = 0; rt < 2; rt++)
#pragma unroll
            for (int r = 0; r < 4; r++) {
                sm[rt][r] += __shfl_xor(sm[rt][r], d, 16);
                sq2[rt][r] += __shfl_xor(sq2[rt][r], d, 16);
            }
    if (lq == 0) {
#pragma unroll
        for (int rt = 0; rt < 2; rt++)
#pragma unroll
            for (int r = 0; r < 4; r++) {
                redS[w][rt * 16 + quad * 4 + r] = sm[rt][r];
                redS2[w][rt * 16 + quad * 4 + r] = sq2[rt][r];
            }
    }
    __syncthreads();
#pragma unroll
    for (int rt = 0; rt < 2; rt++)
#pragma unroll
        for (int r = 0; r < 4; r++) {
            int row = rt * 16 + quad * 4 + r;
            float s1 = redS[0][row] + redS[1][row] + redS[2][row] + redS[3][row];
            float s2 = redS2[0][row] + redS2[1][row] + redS2[2][row] + redS2[3][row];
            float mu = s1 * (1.0f / H);
            float var = s2 * (1.0f / H) - mu * mu;
            float inv = rsqrtf(fmaxf(var, 0.0f) + 1e-5f);
#pragma unroll
            for (int ct = 0; ct < 4; ct++) {
                int col = w * 64 + ct * 16 + lq;
                out[(size_t)(p0 + row) * H + col] =
                    (x[rt][ct][r] - mu) * inv * gamma[col] + beta[col];
            }
        }
}

// ---------------------------------------------------------------------------
extern "C" void kernel_launch(void* const* d_in, const int* in_sizes, int n_in,
                              void* d_out, int out_size, void* d_ws, size_t ws_size,
                              hipStream_t stream) {
    const float* feat    = (const float*)d_in[0];
    const float* centers = (const float*)d_in[1];
    const float* textg   = (const float*)d_in[2];
    const float* w1      = (const float*)d_in[3];
    const float* b1      = (const float*)d_in[4];
    const float* w2      = (const float*)d_in[5];
    const float* b2      = (const float*)d_in[6];
    const float* wg      = (const float*)d_in[7];
    const float* bg      = (const float*)d_in[8];
    const float* wtb     = (const float*)d_in[9];
    const float* btb     = (const float*)d_in[10];
    const float* we1     = (const float*)d_in[11];
    const float* be1     = (const float*)d_in[12];
    const float* we2     = (const float*)d_in[13];
    const float* be2     = (const float*)d_in[14];
    const float* wm      = (const float*)d_in[15];
    const float* bm      = (const float*)d_in[16];
    const float* wo      = (const float*)d_in[17];
    const float* bo      = (const float*)d_in[18];
    const float* gamma   = (const float*)d_in[19];
    const float* beta    = (const float*)d_in[20];

    char* ws = (char*)d_ws;
    size_t off = 0;
    int* knn     = (int*)(ws + off);   off += (size_t)BB * NPT * KNN * 4;   // 1 MB
    float* gate  = (float*)(ws + off); off += (size_t)BB * H * 4;           // 64 KB
    float* tbias = (float*)(ws + off); off += (size_t)BB * H * 4;           // 64 KB
    u16* MSGB    = (u16*)(ws + off);   off += (size_t)BB * NPT * H * 2;     // 8 MB
    u16* ctxB    = (u16*)(ws + off);   off += (size_t)BB * NPT * H * 2;     // 8 MB
    u16* w2t     = (u16*)(ws + off);   off += (size_t)256 * 256 * 2;        // 128 KB
    u16* we1t    = (u16*)(ws + off);   off += (size_t)128 * 256 * 2;        // 64 KB
    u16* wmt     = (u16*)(ws + off);   off += (size_t)256 * 256 * 2;        // 128 KB
    u16* wot     = (u16*)(ws + off);   off += (size_t)256 * 512 * 2;        // 256 KB
    u16* w1t     = (u16*)(ws + off);   off += (size_t)256 * 32 * 2;         // 16 KB

    prep_kernel<<<73, 256, 0, stream>>>(w2, we1, wm, wo, w1, b1,
                                        w2t, we1t, wmt, wot, w1t);
    knn_kernel<<<256, 256, 0, stream>>>(centers, knn);
    gate_kernel<<<BB, 1024, 0, stream>>>(textg, wg, bg, wtb, btb, gate, tbias);
    msg_mfma<<<BB * NPT / 64, 256, 0, stream>>>(feat, wmt, bm, MSGB);
    edge_mfma<<<BB * NPT / 4, 256, 0, stream>>>(feat, centers, w1t, w2t, b2,
                                                we1t, be1, we2, be2, knn, gate, tbias,
                                                MSGB, ctxB);
    out_mfma<<<BB * NPT / 32, 256, 0, stream>>>(feat, ctxB, wot, bo,
                                                gamma, beta, (float*)d_out);
}

// Round 7
// 325.617 us; speedup vs baseline: 1.0942x; 1.0503x over previous
//
#include <hip/hip_runtime.h>
#include <hip/hip_bf16.h>

#define H 256
#define KNN 16
#define NPT 256
#define BB 64

typedef unsigned short u16;
typedef unsigned int u32;
typedef __attribute__((ext_vector_type(8))) short shortx8;
typedef __attribute__((ext_vector_type(4))) float floatx4;

// RNE f32->bf16 via hw cvt; same rounding as manual (u + 0x7fff + lsb) >> 16.
__device__ __forceinline__ u16 f2b(float f) {
    return __builtin_bit_cast(u16, __float2bfloat16(f));
}
__device__ __forceinline__ float b2f(u16 u) {
    return __uint_as_float(((u32)u) << 16);
}

// tanh via hw exp2: 1 - 2/(exp2(x*2log2e)+1). |err| ~1e-6, saturates correctly.
__device__ __forceinline__ float fast_tanh(float x) {
    float e = __builtin_amdgcn_exp2f(x * 2.88539008177793f);
    return 1.0f - 2.0f * __builtin_amdgcn_rcpf(e + 1.0f);
}

// ---------------------------------------------------------------------------
// Session ledger:
// R10: edge M=64 interleaved gathers 146us PROVEN. R11: reg prefetch spills
//      (+75). R12: global_load_lds staging serializes (+4). R13: edge M=32
//      -> per-block fixed cost (weights/barriers) dominates (+92). R14:
//      epilogue reorder 146->138. R15: featB removed, total -2 only ->
//      reset cost not ~ ws bytes; setprio null. Total 336 BEST. R16: msg/out
//      tile-halving repeated R13's mistake (+20, reverted). R17: XCD batch
//      swizzle: FETCH 88.6->13.9MB (L2-residency confirmed) but dur flat ->
//      gathers were already latency-hidden; edge NOT memory-bound.
// DISPATCH-ID FACT: ~64 dispatches/iter, 6 ours -> ~200us harness floor.
// R18: the one untested lever, backed by R13+m93: GROW the tile. M=128
//      (8 pts/block, 2048 blocks): halves total weight-L2 traffic
//      (786->393MB, ~-11us) + halves barrier/fixed overhead + 2x MFMA per
//      B-frag load. acc[8][4]=128 AGPR -> launch_bounds(256,2) (unified
//      file ~188/256). LDS 71.5KB (fnS dropped; fn re-read from L2-warm
//      feat) -> 2 blocks/CU. Swizzle KEPT (TLP halves -> L2-hit gathers now
//      load-bearing). PRE-COMMIT: edge>=145 -> revert to R15, declare floor.
// ---------------------------------------------------------------------------
// K0: prep — LDS 64x64 tiled transpose, coalesced both sides.
// ---------------------------------------------------------------------------
__global__ __launch_bounds__(256) void prep_kernel(
    const float* __restrict__ w2, const float* __restrict__ we1,
    const float* __restrict__ wm, const float* __restrict__ wo,
    const float* __restrict__ w1, const float* __restrict__ b1,
    u16* __restrict__ w2t, u16* __restrict__ we1t,
    u16* __restrict__ wmt, u16* __restrict__ wot, u16* __restrict__ w1t) {
    int bid = blockIdx.x, t = threadIdx.x;
    if (bid == 72) {  // w1t: 256 x 32, k<4 from w1, k==4 bias row, else 0
        for (int e = t; e < 8192; e += 256) {
            int n = e >> 5, k = e & 31;
            float v = (k < 4) ? w1[k * 256 + n] : (k == 4 ? b1[n] : 0.0f);
            w1t[e] = f2b(v);
        }
        return;
    }
    const float* in; u16* outp; int K, N, kt, nt;
    if (bid < 16)      { in = w2;  outp = w2t;  K = 256; N = 256; int q = bid;      kt = q >> 2; nt = q & 3; }
    else if (bid < 24) { in = we1; outp = we1t; K = 256; N = 128; int q = bid - 16; kt = q >> 1; nt = q & 1; }
    else if (bid < 40) { in = wm;  outp = wmt;  K = 256; N = 256; int q = bid - 24; kt = q >> 2; nt = q & 3; }
    else               { in = wo;  outp = wot;  K = 512; N = 256; int q = bid - 40; kt = q >> 2; nt = q & 3; }
    __shared__ u16 T[64][66];
    int c = t & 63, r0 = t >> 6;
#pragma unroll
    for (int i = 0; i < 16; i++) {
        int r = r0 + i * 4;
        T[r][c] = f2b(in[(size_t)(kt * 64 + r) * N + nt * 64 + c]);  // coalesced
    }
    __syncthreads();
#pragma unroll
    for (int i = 0; i < 16; i++) {
        int r = r0 + i * 4;  // output row (n-dim)
        outp[(size_t)(nt * 64 + r) * K + kt * 64 + c] = T[c][r];     // coalesced
    }
}

// ---------------------------------------------------------------------------
// K1: exact KNN k=16, stable (d, idx)-lexicographic == jax.lax.top_k(-dist).
// ---------------------------------------------------------------------------
__global__ __launch_bounds__(256) void knn_kernel(const float* __restrict__ centers,
                                                  int* __restrict__ knn) {
    __shared__ float cx[NPT], cy[NPT], cz[NPT], sq[NPT];
    __shared__ float dl[4][64][17];
    __shared__ int il[4][64][17];
    int blk = blockIdx.x;
    int b = blk >> 2, n0 = (blk & 3) * 64;
    int h = threadIdx.x;
    int s = h >> 6, pt = h & 63;
    {
        const float* cb = centers + (size_t)b * NPT * 3;
        float x = cb[h * 3 + 0], y = cb[h * 3 + 1], z = cb[h * 3 + 2];
        cx[h] = x; cy[h] = y; cz[h] = z;
        sq[h] = x * x + y * y + z * z;
    }
    __syncthreads();
    int n = n0 + pt;
    float x = cx[n], y = cy[n], z = cz[n], sn = sq[n];
    float bd[KNN];
    int bi[KNN];
#pragma unroll
    for (int j = 0; j < KNN; j++) { bd[j] = 1e30f; bi[j] = 0x7fffffff; }
    for (int mm = 0; mm < 64; mm++) {
        int m = s * 64 + mm;
        float dot = x * cx[m] + y * cy[m] + z * cz[m];
        float d2 = (sn + sq[m]) - 2.0f * dot;
        float d = sqrtf(fmaxf(d2, 0.0f));
        if (d < bd[KNN - 1]) {  // in-order scan + strict < == lexicographic
            bd[KNN - 1] = d; bi[KNN - 1] = m;
#pragma unroll
            for (int p = KNN - 1; p > 0; --p) {
                if (bd[p - 1] > bd[p]) {
                    float td = bd[p - 1]; bd[p - 1] = bd[p]; bd[p] = td;
                    int ti = bi[p - 1]; bi[p - 1] = bi[p]; bi[p] = ti;
                }
            }
        }
    }
#pragma unroll
    for (int j = 0; j < KNN; j++) { dl[s][pt][j] = bd[j]; il[s][pt][j] = bi[j]; }
    __syncthreads();
    if (s == 0) {
        float md[KNN];
        int mi[KNN];
#pragma unroll
        for (int j = 0; j < KNN; j++) { md[j] = dl[0][pt][j]; mi[j] = il[0][pt][j]; }
        for (int t = 1; t < 4; t++) {
            for (int j = 0; j < KNN; j++) {
                float d = dl[t][pt][j];
                int idx = il[t][pt][j];
                bool ins = (d < md[KNN - 1]) || (d == md[KNN - 1] && idx < mi[KNN - 1]);
                if (!ins) break;  // source list sorted lexicographically
                md[KNN - 1] = d; mi[KNN - 1] = idx;
#pragma unroll
                for (int p = KNN - 1; p > 0; --p) {
                    bool sw = (md[p - 1] > md[p]) ||
                              (md[p - 1] == md[p] && mi[p - 1] > mi[p]);
                    if (sw) {
                        float td = md[p - 1]; md[p - 1] = md[p]; md[p] = td;
                        int ti = mi[p - 1]; mi[p - 1] = mi[p]; mi[p] = ti;
                    }
                }
            }
        }
        int* kp = knn + (b * NPT + n0 + pt) * KNN;
#pragma unroll
        for (int j = 0; j < KNN; j++) kp[j] = mi[j];
    }
}

// ---------------------------------------------------------------------------
// K2: text gate / bias per batch. 1024 threads, dot split 2-way + LDS reduce.
// ---------------------------------------------------------------------------
__global__ __launch_bounds__(1024) void gate_kernel(const float* __restrict__ tg_g,
                                                    const float* __restrict__ wg,
                                                    const float* __restrict__ bg,
                                                    const float* __restrict__ wtb,
                                                    const float* __restrict__ btb,
                                                    float* __restrict__ gate,
                                                    float* __restrict__ tbias) {
    __shared__ float tg[H];
    __shared__ float red[1024];
    int b = blockIdx.x, t = threadIdx.x;
    if (t < H) tg[t] = tg_g[b * H + t];
    __syncthreads();
    int o = t & 511;        // 512 outputs: 0..255 gate, 256..511 tbias
    int half = t >> 9;      // 0 or 1: which half of the K range
    int h = o & 255;
    const float* wsel = (o < 256) ? wg : wtb;
    float a = 0.0f;
#pragma unroll 4
    for (int i = half * 128; i < half * 128 + 128; i++)
        a += tg[i] * wsel[i * H + h];
    red[t] = a;
    __syncthreads();
    if (t < 512) {
        float s = red[t] + red[t + 512];
        if (o < 256) {
            gate[b * H + h] = 1.0f / (1.0f + expf(-(s + bg[h])));
        } else {
            tbias[b * H + h] = s + btb[h];
        }
    }
}

// ---------------------------------------------------------------------------
// K3: MSGB = bf16(relu(feat @ Wm + bm)), MFMA, 64 points/block (R15 config).
// ---------------------------------------------------------------------------
__global__ __launch_bounds__(256, 4) void msg_mfma(const float* __restrict__ feat,
                                                   const u16* __restrict__ wmt,
                                                   const float* __restrict__ bm,
                                                   u16* __restrict__ MSGB) {
    __shared__ __attribute__((aligned(16))) u16 A[64][264];
    int p0 = blockIdx.x * 64, h = threadIdx.x;
    int w = h >> 6, lane = h & 63, quad = lane >> 4, lq = lane & 15;
#pragma unroll 8
    for (int row = 0; row < 64; row++)
        A[row][h] = f2b(feat[(size_t)(p0 + row) * H + h]);
    __syncthreads();
    floatx4 acc[4][4];
#pragma unroll
    for (int rt = 0; rt < 4; rt++)
#pragma unroll
        for (int ct = 0; ct < 4; ct++) acc[rt][ct] = (floatx4){0, 0, 0, 0};
#pragma unroll 2
    for (int kt = 0; kt < 8; kt++) {
        shortx8 bf[4];
#pragma unroll
        for (int ct = 0; ct < 4; ct++)
            bf[ct] = *(const shortx8*)&wmt[(w * 64 + ct * 16 + lq) * 256 + kt * 32 + quad * 8];
#pragma unroll
        for (int rt = 0; rt < 4; rt++) {
            shortx8 a = *(const shortx8*)&A[rt * 16 + lq][kt * 32 + quad * 8];
#pragma unroll
            for (int ct = 0; ct < 4; ct++)
                acc[rt][ct] = __builtin_amdgcn_mfma_f32_16x16x32_bf16(a, bf[ct], acc[rt][ct], 0, 0, 0);
        }
    }
#pragma unroll
    for (int ct = 0; ct < 4; ct++) {
        int col = w * 64 + ct * 16 + lq;
        float bmc = bm[col];
#pragma unroll
        for (int rt = 0; rt < 4; rt++)
#pragma unroll
            for (int r = 0; r < 4; r++) {
                int row = rt * 16 + quad * 4 + r;
                MSGB[(size_t)(p0 + row) * H + col] = f2b(fmaxf(acc[rt][ct][r] + bmc, 0.0f));
            }
    }
}

// ---------------------------------------------------------------------------
// K4: fused edge pipeline. R18: M=128 (8 points/block, 2048 blocks),
// acc[8][4]=128 AGPR, (256,2), LDS 71.5KB -> 2 blocks/CU. fn read from
// global (L2-warm) instead of LDS. Batch-locality XCD swizzle kept.
// ---------------------------------------------------------------------------
__global__ __launch_bounds__(256, 2) void edge_mfma(
    const float* __restrict__ feat,
    const float* __restrict__ centers,
    const u16* __restrict__ w1t,
    const u16* __restrict__ w2t, const float* __restrict__ b2v,
    const u16* __restrict__ we1t, const float* __restrict__ be1,
    const float* __restrict__ we2, const float* __restrict__ be2,
    const int* __restrict__ knn, const float* __restrict__ gateG,
    const float* __restrict__ tbiasG, const u16* __restrict__ MSGB,
    u16* __restrict__ ctxB) {
    __shared__ __attribute__((aligned(16))) u16 A[128][264];  // g1 then edge_feat
    __shared__ __attribute__((aligned(16))) float geomS[128][4];
    __shared__ int nidxS[128];
    __shared__ float part[4][128];
    __shared__ float logitsS[128];
    __shared__ float alphaS[128];

    // Bijective XCD swizzle (2048 blocks, 2048%8==0): XCD x owns batches
    // [8x,8x+8) -> gather working set ~3MB/XCD, L2-resident (R17-proven).
    int wid = (blockIdx.x & 7) * 256 + (blockIdx.x >> 3);
    int bn0 = wid * 8;
    int b = bn0 >> 8, n0 = bn0 & 255;
    int h = threadIdx.x;
    int w = h >> 6, lane = h & 63, quad = lane >> 4, lq = lane & 15;

    // phase 0: nidx (128 edges' neighbor idx; rows 16 per point, 8 points)
    if (h < 128) nidxS[h] = knn[bn0 * KNN + h];
    __syncthreads();
    // phase 1: geom per edge-row (h<128: point p=h>>4, neighbor j=h&15)
    if (h < 128) {
        int p = h >> 4;
        int m = nidxS[h];
        int n = n0 + p;
        const float* cb = centers + (size_t)b * NPT * 3;
        float rx = cb[m * 3 + 0] - cb[n * 3 + 0];
        float ry = cb[m * 3 + 1] - cb[n * 3 + 1];
        float rz = cb[m * 3 + 2] - cb[n * 3 + 2];
        float dist = sqrtf(rx * rx + ry * ry + rz * rz) + 1e-6f;
        geomS[h][0] = rx; geomS[h][1] = ry; geomS[h][2] = rz;
        geomS[h][3] = log1pf(dist);
    }
    __syncthreads();

    // phase 2: g1[128][256] = relu(geomP @ W1t) via MFMA (K=32 pad, k=4 bias)
    {
        shortx8 bw1[4];
#pragma unroll
        for (int ct = 0; ct < 4; ct++)
            bw1[ct] = *(const shortx8*)&w1t[(w * 64 + ct * 16 + lq) * 32 + quad * 8];
#pragma unroll
        for (int rt = 0; rt < 8; rt++) {
            shortx8 ag = {0, 0, 0, 0, 0, 0, 0, 0};
            if (quad == 0) {
                float4 g = *(const float4*)&geomS[rt * 16 + lq][0];
                ag[0] = (short)f2b(g.x);
                ag[1] = (short)f2b(g.y);
                ag[2] = (short)f2b(g.z);
                ag[3] = (short)f2b(g.w);
                ag[4] = (short)0x3F80;  // 1.0 -> multiplies bias row of w1t
            }
#pragma unroll
            for (int ct = 0; ct < 4; ct++) {
                floatx4 accg = __builtin_amdgcn_mfma_f32_16x16x32_bf16(
                    ag, bw1[ct], (floatx4){0, 0, 0, 0}, 0, 0, 0);
#pragma unroll
                for (int r = 0; r < 4; r++)
                    A[rt * 16 + quad * 4 + r][w * 64 + ct * 16 + lq] =
                        f2b(fmaxf(accg[r], 0.0f));
            }
        }
    }
    __syncthreads();

    // GEMM1: C1[128][256] = g1 @ W2 (4 B-frag loads amortize over 8 rt)
    floatx4 acc[8][4];
#pragma unroll
    for (int rt = 0; rt < 8; rt++)
#pragma unroll
        for (int ct = 0; ct < 4; ct++) acc[rt][ct] = (floatx4){0, 0, 0, 0};
    __builtin_amdgcn_s_setprio(1);
    for (int kt = 0; kt < 8; kt++) {
        shortx8 bf[4];
#pragma unroll
        for (int ct = 0; ct < 4; ct++)
            bf[ct] = *(const shortx8*)&w2t[(w * 64 + ct * 16 + lq) * 256 + kt * 32 + quad * 8];
#pragma unroll
        for (int rt = 0; rt < 8; rt++) {
            shortx8 a = *(const shortx8*)&A[rt * 16 + lq][kt * 32 + quad * 8];
#pragma unroll
            for (int ct = 0; ct < 4; ct++)
                acc[rt][ct] = __builtin_amdgcn_mfma_f32_16x16x32_bf16(a, bf[ct], acc[rt][ct], 0, 0, 0);
        }
    }
    __builtin_amdgcn_s_setprio(0);
    __syncthreads();  // all g1 reads done

    // epilogue1: edge_feat = tanh(fn + fb + relu(C1+b2)*gate + tbias) -> A
    // R14 order: (rt,r) outer / ct inner; row base once; col scalars hoisted.
    // fn read from feat global (point row, coalesced, L2-warm; fnS dropped
    // to keep LDS under 2-blocks/CU budget).
    {
        float b2c4[4], gc4[4], tc4[4];
#pragma unroll
        for (int ct = 0; ct < 4; ct++) {
            int col = w * 64 + ct * 16 + lq;
            b2c4[ct] = b2v[col];
            gc4[ct]  = gateG[b * H + col];
            tc4[ct]  = tbiasG[b * H + col];
        }
#pragma unroll
        for (int rt = 0; rt < 8; rt++) {
            const float* fnp = feat + (size_t)(bn0 + rt) * H + w * 64 + lq;
            float fnt4[4];
#pragma unroll
            for (int ct = 0; ct < 4; ct++)
                fnt4[ct] = fnp[ct * 16] + tc4[ct];
#pragma unroll
            for (int r = 0; r < 4; r++) {
                int row = rt * 16 + quad * 4 + r;
                const float* rowp = feat + ((size_t)b * NPT + nidxS[row]) * H + w * 64 + lq;
#pragma unroll
                for (int ct = 0; ct < 4; ct++) {
                    float fb = rowp[ct * 16];
                    float emb = fmaxf(acc[rt][ct][r] + b2c4[ct], 0.0f);
                    A[row][w * 64 + ct * 16 + lq] = f2b(fast_tanh(fnt4[ct] + fb + emb * gc4[ct]));
                }
            }
        }
    }
    __syncthreads();

    // GEMM2: C2[128][128] = edge_feat @ We1
    floatx4 acc2[8][2];
#pragma unroll
    for (int rt = 0; rt < 8; rt++)
#pragma unroll
        for (int c2 = 0; c2 < 2; c2++) acc2[rt][c2] = (floatx4){0, 0, 0, 0};
    __builtin_amdgcn_s_setprio(1);
    for (int kt = 0; kt < 8; kt++) {
        shortx8 bf[2];
#pragma unroll
        for (int c2 = 0; c2 < 2; c2++)
            bf[c2] = *(const shortx8*)&we1t[(w * 32 + c2 * 16 + lq) * 256 + kt * 32 + quad * 8];
#pragma unroll
        for (int rt = 0; rt < 8; rt++) {
            shortx8 a = *(const shortx8*)&A[rt * 16 + lq][kt * 32 + quad * 8];
#pragma unroll
            for (int c2 = 0; c2 < 2; c2++)
                acc2[rt][c2] = __builtin_amdgcn_mfma_f32_16x16x32_bf16(a, bf[c2], acc2[rt][c2], 0, 0, 0);
        }
    }
    __builtin_amdgcn_s_setprio(0);

    // logits partials
    float pl[8][4];
#pragma unroll
    for (int rt = 0; rt < 8; rt++)
#pragma unroll
        for (int r = 0; r < 4; r++) pl[rt][r] = 0.0f;
#pragma unroll
    for (int c2 = 0; c2 < 2; c2++) {
        int col = w * 32 + c2 * 16 + lq;
        float be1c = be1[col], w2c = we2[col];
#pragma unroll
        for (int rt = 0; rt < 8; rt++)
#pragma unroll
            for (int r = 0; r < 4; r++)
                pl[rt][r] += fmaxf(acc2[rt][c2][r] + be1c, 0.0f) * w2c;
    }
#pragma unroll
    for (int d = 1; d < 16; d <<= 1)
#pragma unroll
        for (int rt = 0; rt < 8; rt++)
#pragma unroll
            for (int r = 0; r < 4; r++) pl[rt][r] += __shfl_xor(pl[rt][r], d, 16);
    if (lq == 0) {
#pragma unroll
        for (int rt = 0; rt < 8; rt++)
#pragma unroll
            for (int r = 0; r < 4; r++)
                part[w][rt * 16 + quad * 4 + r] = pl[rt][r];
    }
    __syncthreads();
    if (h < 128)
        logitsS[h] = part[0][h] + part[1][h] + part[2][h] + part[3][h] + be2[0];
    __syncthreads();
    if (h < 128) {
        int base = (h >> 4) * 16;
        float mx = -1e30f;
#pragma unroll
        for (int j = 0; j < KNN; j++) mx = fmaxf(mx, logitsS[base + j]);
        float sum = 0.0f;
#pragma unroll
        for (int j = 0; j < KNN; j++) sum += expf(logitsS[base + j] - mx);
        alphaS[h] = expf(logitsS[h] - mx) / sum;
    }
    __syncthreads();

    // ctx: 2 passes; thread -> (point p, 4 cols); bf16 gather over 16 nbrs.
#pragma unroll
    for (int pp = 0; pp < 2; pp++) {
        int p = pp * 4 + (h >> 6), cg = (h & 63) * 4;
        float4 c = {0, 0, 0, 0};
#pragma unroll
        for (int j = 0; j < KNN; j++) {
            float al = alphaS[p * 16 + j];
            const u32* mp = (const u32*)&MSGB[((size_t)b * NPT + nidxS[p * 16 + j]) * H + cg];
            u32 m0 = mp[0], m1 = mp[1];
            c.x += al * __uint_as_float(m0 << 16);
            c.y += al * __uint_as_float(m0 & 0xFFFF0000u);
            c.z += al * __uint_as_float(m1 << 16);
            c.w += al * __uint_as_float(m1 & 0xFFFF0000u);
        }
        uint2 st;
        st.x = (u32)f2b(c.x) | ((u32)f2b(c.y) << 16);
        st.y = (u32)f2b(c.z) | ((u32)f2b(c.w) << 16);
        *(uint2*)&ctxB[(size_t)(bn0 + p) * H + cg] = st;
    }
}

// ---------------------------------------------------------------------------
// K5: out = LN(feat + relu([feat|ctx] @ Wo + bo)), MFMA, 32 points/block.
// ---------------------------------------------------------------------------
__global__ __launch_bounds__(256, 4) void out_mfma(const float* __restrict__ feat,
                                                   const u16* __restrict__ ctxB,
                                                   const u16* __restrict__ wot,
                                                   const float* __restrict__ bo,
                                                   const float* __restrict__ gamma,
                                                   const float* __restrict__ beta,
                                                   float* __restrict__ out) {
    __shared__ __attribute__((aligned(16))) u16 A[32][520];
    __shared__ float redS[4][32], redS2[4][32];
    int p0 = blockIdx.x * 32, h = threadIdx.x;
    int w = h >> 6, lane = h & 63, quad = lane >> 4, lq = lane & 15;
#pragma unroll 8
    for (int row = 0; row < 32; row++) {
        A[row][h]       = f2b(feat[(size_t)(p0 + row) * H + h]);
        A[row][256 + h] = ctxB[(size_t)(p0 + row) * H + h];
    }
    __syncthreads();
    floatx4 acc[2][4];
#pragma unroll
    for (int rt = 0; rt < 2; rt++)
#pragma unroll
        for (int ct = 0; ct < 4; ct++) acc[rt][ct] = (floatx4){0, 0, 0, 0};
#pragma unroll 2
    for (int kt = 0; kt < 16; kt++) {
        shortx8 bf[4];
#pragma unroll
        for (int ct = 0; ct < 4; ct++)
            bf[ct] = *(const shortx8*)&wot[(w * 64 + ct * 16 + lq) * 512 + kt * 32 + quad * 8];
#pragma unroll
        for (int rt = 0; rt < 2; rt++) {
            shortx8 a = *(const shortx8*)&A[rt * 16 + lq][kt * 32 + quad * 8];
#pragma unroll
            for (int ct = 0; ct < 4; ct++)
                acc[rt][ct] = __builtin_amdgcn_mfma_f32_16x16x32_bf16(a, bf[ct], acc[rt][ct], 0, 0, 0);
        }
    }
    float x[2][4][4];
    float sm[2][4], sq2[2][4];
#pragma unroll
    for (int rt = 0; rt < 2; rt++)
#pragma unroll
        for (int r = 0; r < 4; r++) { sm[rt][r] = 0.0f; sq2[rt][r] = 0.0f; }
#pragma unroll
    for (int rt = 0; rt < 2; rt++)
#pragma unroll
        for (int ct = 0; ct < 4; ct++) {
            int col = w * 64 + ct * 16 + lq;
            float boc = bo[col];
#pragma unroll
            for (int r = 0; r < 4; r++) {
                int row = rt * 16 + quad * 4 + r;
                float xx = feat[(size_t)(p0 + row) * H + col] +
                           fmaxf(acc[rt][ct][r] + boc, 0.0f);
                x[rt][ct][r] = xx;
                sm[rt][r] += xx;
                sq2[rt][r] += xx * xx;
            }
        }
#pragma unroll
    for (int d = 1; d < 16; d <<= 1)
#pragma unroll
        for (int rt = 0; rt < 2; rt++)
#pragma unroll
            for (int r = 0; r < 4; r++) {
                sm[rt][r] += __shfl_xor(sm[rt][r], d, 16);
                sq2[rt][r] += __shfl_xor(sq2[rt][r], d, 16);
            }
    if (lq == 0) {
#pragma unroll
        for (int rt = 0; rt < 2; rt++)
#pragma unroll
            for (int r = 0; r < 4; r++) {
                redS[w][rt * 16 + quad * 4 + r] = sm[rt][r];
                redS2[w][rt * 16 + quad * 4 + r] = sq2[rt][r];
            }
    }
    __syncthreads();
#pragma unroll
    for (int rt = 0; rt < 2; rt++)
#pragma unroll
        for (int r = 0; r < 4; r++) {
            int row = rt * 16 + quad * 4 + r;
            float s1 = redS[0][row] + redS[1][row] + redS[2][row] + redS[3][row];
            float s2 = redS2[0][row] + redS2[1][row] + redS2[2][row] + redS2[3][row];
            float mu = s1 * (1.0f / H);
            float var = s2 * (1.0f / H) - mu * mu;
            float inv = rsqrtf(fmaxf(var, 0.0f) + 1e-5f);
#pragma unroll
            for (int ct = 0; ct < 4; ct++) {
                int col = w * 64 + ct * 16 + lq;
                out[(size_t)(p0 + row) * H + col] =
                    (x[rt][ct][r] - mu) * inv * gamma[col] + beta[col];
            }
        }
}

// ---------------------------------------------------------------------------
extern "C" void kernel_launch(void* const* d_in, const int* in_sizes, int n_in,
                              void* d_out, int out_size, void* d_ws, size_t ws_size,
                              hipStream_t stream) {
    const float* feat    = (const float*)d_in[0];
    const float* centers = (const float*)d_in[1];
    const float* textg   = (const float*)d_in[2];
    const float* w1      = (const float*)d_in[3];
    const float* b1      = (const float*)d_in[4];
    const float* w2      = (const float*)d_in[5];
    const float* b2      = (const float*)d_in[6];
    const float* wg      = (const float*)d_in[7];
    const float* bg      = (const float*)d_in[8];
    const float* wtb     = (const float*)d_in[9];
    const float* btb     = (const float*)d_in[10];
    const float* we1     = (const float*)d_in[11];
    const float* be1     = (const float*)d_in[12];
    const float* we2     = (const float*)d_in[13];
    const float* be2     = (const float*)d_in[14];
    const float* wm      = (const float*)d_in[15];
    const float* bm      = (const float*)d_in[16];
    const float* wo      = (const float*)d_in[17];
    const float* bo      = (const float*)d_in[18];
    const float* gamma   = (const float*)d_in[19];
    const float* beta    = (const float*)d_in[20];

    char* ws = (char*)d_ws;
    size_t off = 0;
    int* knn     = (int*)(ws + off);   off += (size_t)BB * NPT * KNN * 4;   // 1 MB
    float* gate  = (float*)(ws + off); off += (size_t)BB * H * 4;           // 64 KB
    float* tbias = (float*)(ws + off); off += (size_t)BB * H * 4;           // 64 KB
    u16* MSGB    = (u16*)(ws + off);   off += (size_t)BB * NPT * H * 2;     // 8 MB
    u16* ctxB    = (u16*)(ws + off);   off += (size_t)BB * NPT * H * 2;     // 8 MB
    u16* w2t     = (u16*)(ws + off);   off += (size_t)256 * 256 * 2;        // 128 KB
    u16* we1t    = (u16*)(ws + off);   off += (size_t)128 * 256 * 2;        // 64 KB
    u16* wmt     = (u16*)(ws + off);   off += (size_t)256 * 256 * 2;        // 128 KB
    u16* wot     = (u16*)(ws + off);   off += (size_t)256 * 512 * 2;        // 256 KB
    u16* w1t     = (u16*)(ws + off);   off += (size_t)256 * 32 * 2;         // 16 KB

    prep_kernel<<<73, 256, 0, stream>>>(w2, we1, wm, wo, w1, b1,
                                        w2t, we1t, wmt, wot, w1t);
    knn_kernel<<<256, 256, 0, stream>>>(centers, knn);
    gate_kernel<<<BB, 1024, 0, stream>>>(textg, wg, bg, wtb, btb, gate, tbias);
    msg_mfma<<<BB * NPT / 64, 256, 0, stream>>>(feat, wmt, bm, MSGB);
    edge_mfma<<<BB * NPT / 8, 256, 0, stream>>>(feat, centers, w1t, w2t, b2,
                                                we1t, be1, we2, be2, knn, gate, tbias,
                                                MSGB, ctxB);
    out_mfma<<<BB * NPT / 32, 256, 0, stream>>>(feat, ctxB, wot, bo,
                                                gamma, beta, (float*)d_out);
}

// Round 8
// 320.449 us; speedup vs baseline: 1.1119x; 1.0161x over previous
//
#include <hip/hip_runtime.h>
#include <hip/hip_bf16.h>

#define H 256
#define KNN 16
#define NPT 256
#define BB 64

typedef unsigned short u16;
typedef unsigned int u32;
typedef __attribute__((ext_vector_type(8))) short shortx8;
typedef __attribute__((ext_vector_type(4))) float floatx4;

// RNE f32->bf16 via hw cvt; same rounding as manual (u + 0x7fff + lsb) >> 16.
__device__ __forceinline__ u16 f2b(float f) {
    return __builtin_bit_cast(u16, __float2bfloat16(f));
}
__device__ __forceinline__ float b2f(u16 u) {
    return __uint_as_float(((u32)u) << 16);
}

// tanh via hw exp2: 1 - 2/(exp2(x*2log2e)+1). |err| ~1e-6, saturates correctly.
__device__ __forceinline__ float fast_tanh(float x) {
    float e = __builtin_amdgcn_exp2f(x * 2.88539008177793f);
    return 1.0f - 2.0f * __builtin_amdgcn_rcpf(e + 1.0f);
}

// ---------------------------------------------------------------------------
// Session ledger:
// R10: edge M=64 interleaved gathers 146us PROVEN. R11: reg prefetch spills
//      (+75). R12: global_load_lds staging serializes (+4). R13: edge M=32
//      -> per-block fixed cost (weights/barriers) dominates (+92). R14:
//      epilogue reorder 146->138. R15: featB removed, total -2 only ->
//      reset cost not ~ ws bytes; setprio null. R16: msg/out tile-halving
//      repeated R13's mistake (+20, reverted). R17: XCD batch swizzle:
//      FETCH 88.6->13.9MB (L2-residency confirmed) but dur flat -> gathers
//      already latency-hidden. R18: edge M=128 (amortize weights/barriers):
//      137->118us, total 325.6 BEST. Amortization model confirmed both
//      directions (M=32 +92, M=128 -19).
// DISPATCH-ID FACT: ~64 dispatches/iter, 6 ours -> ~200us harness floor.
// R19: same amortization applied to out_mfma: M=32->64 (wot traffic
//      128->64MB, blocks 512->256). Edge FROZEN (32x32-MFMA rewrite is the
//      only edge lever left; high risk, est -8us — not worth it).
//      PRE-COMMIT: total drop <2us -> non-edge is harness floor, declare
//      structural floor next round.
// ---------------------------------------------------------------------------
// K0: prep — LDS 64x64 tiled transpose, coalesced both sides.
// ---------------------------------------------------------------------------
__global__ __launch_bounds__(256) void prep_kernel(
    const float* __restrict__ w2, const float* __restrict__ we1,
    const float* __restrict__ wm, const float* __restrict__ wo,
    const float* __restrict__ w1, const float* __restrict__ b1,
    u16* __restrict__ w2t, u16* __restrict__ we1t,
    u16* __restrict__ wmt, u16* __restrict__ wot, u16* __restrict__ w1t) {
    int bid = blockIdx.x, t = threadIdx.x;
    if (bid == 72) {  // w1t: 256 x 32, k<4 from w1, k==4 bias row, else 0
        for (int e = t; e < 8192; e += 256) {
            int n = e >> 5, k = e & 31;
            float v = (k < 4) ? w1[k * 256 + n] : (k == 4 ? b1[n] : 0.0f);
            w1t[e] = f2b(v);
        }
        return;
    }
    const float* in; u16* outp; int K, N, kt, nt;
    if (bid < 16)      { in = w2;  outp = w2t;  K = 256; N = 256; int q = bid;      kt = q >> 2; nt = q & 3; }
    else if (bid < 24) { in = we1; outp = we1t; K = 256; N = 128; int q = bid - 16; kt = q >> 1; nt = q & 1; }
    else if (bid < 40) { in = wm;  outp = wmt;  K = 256; N = 256; int q = bid - 24; kt = q >> 2; nt = q & 3; }
    else               { in = wo;  outp = wot;  K = 512; N = 256; int q = bid - 40; kt = q >> 2; nt = q & 3; }
    __shared__ u16 T[64][66];
    int c = t & 63, r0 = t >> 6;
#pragma unroll
    for (int i = 0; i < 16; i++) {
        int r = r0 + i * 4;
        T[r][c] = f2b(in[(size_t)(kt * 64 + r) * N + nt * 64 + c]);  // coalesced
    }
    __syncthreads();
#pragma unroll
    for (int i = 0; i < 16; i++) {
        int r = r0 + i * 4;  // output row (n-dim)
        outp[(size_t)(nt * 64 + r) * K + kt * 64 + c] = T[c][r];     // coalesced
    }
}

// ---------------------------------------------------------------------------
// K1: exact KNN k=16, stable (d, idx)-lexicographic == jax.lax.top_k(-dist).
// ---------------------------------------------------------------------------
__global__ __launch_bounds__(256) void knn_kernel(const float* __restrict__ centers,
                                                  int* __restrict__ knn) {
    __shared__ float cx[NPT], cy[NPT], cz[NPT], sq[NPT];
    __shared__ float dl[4][64][17];
    __shared__ int il[4][64][17];
    int blk = blockIdx.x;
    int b = blk >> 2, n0 = (blk & 3) * 64;
    int h = threadIdx.x;
    int s = h >> 6, pt = h & 63;
    {
        const float* cb = centers + (size_t)b * NPT * 3;
        float x = cb[h * 3 + 0], y = cb[h * 3 + 1], z = cb[h * 3 + 2];
        cx[h] = x; cy[h] = y; cz[h] = z;
        sq[h] = x * x + y * y + z * z;
    }
    __syncthreads();
    int n = n0 + pt;
    float x = cx[n], y = cy[n], z = cz[n], sn = sq[n];
    float bd[KNN];
    int bi[KNN];
#pragma unroll
    for (int j = 0; j < KNN; j++) { bd[j] = 1e30f; bi[j] = 0x7fffffff; }
    for (int mm = 0; mm < 64; mm++) {
        int m = s * 64 + mm;
        float dot = x * cx[m] + y * cy[m] + z * cz[m];
        float d2 = (sn + sq[m]) - 2.0f * dot;
        float d = sqrtf(fmaxf(d2, 0.0f));
        if (d < bd[KNN - 1]) {  // in-order scan + strict < == lexicographic
            bd[KNN - 1] = d; bi[KNN - 1] = m;
#pragma unroll
            for (int p = KNN - 1; p > 0; --p) {
                if (bd[p - 1] > bd[p]) {
                    float td = bd[p - 1]; bd[p - 1] = bd[p]; bd[p] = td;
                    int ti = bi[p - 1]; bi[p - 1] = bi[p]; bi[p] = ti;
                }
            }
        }
    }
#pragma unroll
    for (int j = 0; j < KNN; j++) { dl[s][pt][j] = bd[j]; il[s][pt][j] = bi[j]; }
    __syncthreads();
    if (s == 0) {
        float md[KNN];
        int mi[KNN];
#pragma unroll
        for (int j = 0; j < KNN; j++) { md[j] = dl[0][pt][j]; mi[j] = il[0][pt][j]; }
        for (int t = 1; t < 4; t++) {
            for (int j = 0; j < KNN; j++) {
                float d = dl[t][pt][j];
                int idx = il[t][pt][j];
                bool ins = (d < md[KNN - 1]) || (d == md[KNN - 1] && idx < mi[KNN - 1]);
                if (!ins) break;  // source list sorted lexicographically
                md[KNN - 1] = d; mi[KNN - 1] = idx;
#pragma unroll
                for (int p = KNN - 1; p > 0; --p) {
                    bool sw = (md[p - 1] > md[p]) ||
                              (md[p - 1] == md[p] && mi[p - 1] > mi[p]);
                    if (sw) {
                        float td = md[p - 1]; md[p - 1] = md[p]; md[p] = td;
                        int ti = mi[p - 1]; mi[p - 1] = mi[p]; mi[p] = ti;
                    }
                }
            }
        }
        int* kp = knn + (b * NPT + n0 + pt) * KNN;
#pragma unroll
        for (int j = 0; j < KNN; j++) kp[j] = mi[j];
    }
}

// ---------------------------------------------------------------------------
// K2: text gate / bias per batch. 1024 threads, dot split 2-way + LDS reduce.
// ---------------------------------------------------------------------------
__global__ __launch_bounds__(1024) void gate_kernel(const float* __restrict__ tg_g,
                                                    const float* __restrict__ wg,
                                                    const float* __restrict__ bg,
                                                    const float* __restrict__ wtb,
                                                    const float* __restrict__ btb,
                                                    float* __restrict__ gate,
                                                    float* __restrict__ tbias) {
    __shared__ float tg[H];
    __shared__ float red[1024];
    int b = blockIdx.x, t = threadIdx.x;
    if (t < H) tg[t] = tg_g[b * H + t];
    __syncthreads();
    int o = t & 511;        // 512 outputs: 0..255 gate, 256..511 tbias
    int half = t >> 9;      // 0 or 1: which half of the K range
    int h = o & 255;
    const float* wsel = (o < 256) ? wg : wtb;
    float a = 0.0f;
#pragma unroll 4
    for (int i = half * 128; i < half * 128 + 128; i++)
        a += tg[i] * wsel[i * H + h];
    red[t] = a;
    __syncthreads();
    if (t < 512) {
        float s = red[t] + red[t + 512];
        if (o < 256) {
            gate[b * H + h] = 1.0f / (1.0f + expf(-(s + bg[h])));
        } else {
            tbias[b * H + h] = s + btb[h];
        }
    }
}

// ---------------------------------------------------------------------------
// K3: MSGB = bf16(relu(feat @ Wm + bm)), MFMA, 64 points/block (R15 config).
// ---------------------------------------------------------------------------
__global__ __launch_bounds__(256, 4) void msg_mfma(const float* __restrict__ feat,
                                                   const u16* __restrict__ wmt,
                                                   const float* __restrict__ bm,
                                                   u16* __restrict__ MSGB) {
    __shared__ __attribute__((aligned(16))) u16 A[64][264];
    int p0 = blockIdx.x * 64, h = threadIdx.x;
    int w = h >> 6, lane = h & 63, quad = lane >> 4, lq = lane & 15;
#pragma unroll 8
    for (int row = 0; row < 64; row++)
        A[row][h] = f2b(feat[(size_t)(p0 + row) * H + h]);
    __syncthreads();
    floatx4 acc[4][4];
#pragma unroll
    for (int rt = 0; rt < 4; rt++)
#pragma unroll
        for (int ct = 0; ct < 4; ct++) acc[rt][ct] = (floatx4){0, 0, 0, 0};
#pragma unroll 2
    for (int kt = 0; kt < 8; kt++) {
        shortx8 bf[4];
#pragma unroll
        for (int ct = 0; ct < 4; ct++)
            bf[ct] = *(const shortx8*)&wmt[(w * 64 + ct * 16 + lq) * 256 + kt * 32 + quad * 8];
#pragma unroll
        for (int rt = 0; rt < 4; rt++) {
            shortx8 a = *(const shortx8*)&A[rt * 16 + lq][kt * 32 + quad * 8];
#pragma unroll
            for (int ct = 0; ct < 4; ct++)
                acc[rt][ct] = __builtin_amdgcn_mfma_f32_16x16x32_bf16(a, bf[ct], acc[rt][ct], 0, 0, 0);
        }
    }
#pragma unroll
    for (int ct = 0; ct < 4; ct++) {
        int col = w * 64 + ct * 16 + lq;
        float bmc = bm[col];
#pragma unroll
        for (int rt = 0; rt < 4; rt++)
#pragma unroll
            for (int r = 0; r < 4; r++) {
                int row = rt * 16 + quad * 4 + r;
                MSGB[(size_t)(p0 + row) * H + col] = f2b(fmaxf(acc[rt][ct][r] + bmc, 0.0f));
            }
    }
}

// ---------------------------------------------------------------------------
// K4: fused edge pipeline. R18 PROVEN: M=128 (8 points/block, 2048 blocks),
// acc[8][4]=128 AGPR, (256,2), LDS 71.5KB -> 2 blocks/CU. fn read from
// global (L2-warm). Batch-locality XCD swizzle. FROZEN.
// ---------------------------------------------------------------------------
__global__ __launch_bounds__(256, 2) void edge_mfma(
    const float* __restrict__ feat,
    const float* __restrict__ centers,
    const u16* __restrict__ w1t,
    const u16* __restrict__ w2t, const float* __restrict__ b2v,
    const u16* __restrict__ we1t, const float* __restrict__ be1,
    const float* __restrict__ we2, const float* __restrict__ be2,
    const int* __restrict__ knn, const float* __restrict__ gateG,
    const float* __restrict__ tbiasG, const u16* __restrict__ MSGB,
    u16* __restrict__ ctxB) {
    __shared__ __attribute__((aligned(16))) u16 A[128][264];  // g1 then edge_feat
    __shared__ __attribute__((aligned(16))) float geomS[128][4];
    __shared__ int nidxS[128];
    __shared__ float part[4][128];
    __shared__ float logitsS[128];
    __shared__ float alphaS[128];

    // Bijective XCD swizzle (2048 blocks, 2048%8==0): XCD x owns batches
    // [8x,8x+8) -> gather working set ~3MB/XCD, L2-resident (R17-proven).
    int wid = (blockIdx.x & 7) * 256 + (blockIdx.x >> 3);
    int bn0 = wid * 8;
    int b = bn0 >> 8, n0 = bn0 & 255;
    int h = threadIdx.x;
    int w = h >> 6, lane = h & 63, quad = lane >> 4, lq = lane & 15;

    // phase 0: nidx (128 edges' neighbor idx; rows 16 per point, 8 points)
    if (h < 128) nidxS[h] = knn[bn0 * KNN + h];
    __syncthreads();
    // phase 1: geom per edge-row (h<128: point p=h>>4, neighbor j=h&15)
    if (h < 128) {
        int p = h >> 4;
        int m = nidxS[h];
        int n = n0 + p;
        const float* cb = centers + (size_t)b * NPT * 3;
        float rx = cb[m * 3 + 0] - cb[n * 3 + 0];
        float ry = cb[m * 3 + 1] - cb[n * 3 + 1];
        float rz = cb[m * 3 + 2] - cb[n * 3 + 2];
        float dist = sqrtf(rx * rx + ry * ry + rz * rz) + 1e-6f;
        geomS[h][0] = rx; geomS[h][1] = ry; geomS[h][2] = rz;
        geomS[h][3] = log1pf(dist);
    }
    __syncthreads();

    // phase 2: g1[128][256] = relu(geomP @ W1t) via MFMA (K=32 pad, k=4 bias)
    {
        shortx8 bw1[4];
#pragma unroll
        for (int ct = 0; ct < 4; ct++)
            bw1[ct] = *(const shortx8*)&w1t[(w * 64 + ct * 16 + lq) * 32 + quad * 8];
#pragma unroll
        for (int rt = 0; rt < 8; rt++) {
            shortx8 ag = {0, 0, 0, 0, 0, 0, 0, 0};
            if (quad == 0) {
                float4 g = *(const float4*)&geomS[rt * 16 + lq][0];
                ag[0] = (short)f2b(g.x);
                ag[1] = (short)f2b(g.y);
                ag[2] = (short)f2b(g.z);
                ag[3] = (short)f2b(g.w);
                ag[4] = (short)0x3F80;  // 1.0 -> multiplies bias row of w1t
            }
#pragma unroll
            for (int ct = 0; ct < 4; ct++) {
                floatx4 accg = __builtin_amdgcn_mfma_f32_16x16x32_bf16(
                    ag, bw1[ct], (floatx4){0, 0, 0, 0}, 0, 0, 0);
#pragma unroll
                for (int r = 0; r < 4; r++)
                    A[rt * 16 + quad * 4 + r][w * 64 + ct * 16 + lq] =
                        f2b(fmaxf(accg[r], 0.0f));
            }
        }
    }
    __syncthreads();

    // GEMM1: C1[128][256] = g1 @ W2 (4 B-frag loads amortize over 8 rt)
    floatx4 acc[8][4];
#pragma unroll
    for (int rt = 0; rt < 8; rt++)
#pragma unroll
        for (int ct = 0; ct < 4; ct++) acc[rt][ct] = (floatx4){0, 0, 0, 0};
    __builtin_amdgcn_s_setprio(1);
    for (int kt = 0; kt < 8; kt++) {
        shortx8 bf[4];
#pragma unroll
        for (int ct = 0; ct < 4; ct++)
            bf[ct] = *(const shortx8*)&w2t[(w * 64 + ct * 16 + lq) * 256 + kt * 32 + quad * 8];
#pragma unroll
        for (int rt = 0; rt < 8; rt++) {
            shortx8 a = *(const shortx8*)&A[rt * 16 + lq][kt * 32 + quad * 8];
#pragma unroll
            for (int ct = 0; ct < 4; ct++)
                acc[rt][ct] = __builtin_amdgcn_mfma_f32_16x16x32_bf16(a, bf[ct], acc[rt][ct], 0, 0, 0);
        }
    }
    __builtin_amdgcn_s_setprio(0);
    __syncthreads();  // all g1 reads done

    // epilogue1: edge_feat = tanh(fn + fb + relu(C1+b2)*gate + tbias) -> A
    // R14 order: (rt,r) outer / ct inner; row base once; col scalars hoisted.
    // fn read from feat global (point row, coalesced, L2-warm).
    {
        float b2c4[4], gc4[4], tc4[4];
#pragma unroll
        for (int ct = 0; ct < 4; ct++) {
            int col = w * 64 + ct * 16 + lq;
            b2c4[ct] = b2v[col];
            gc4[ct]  = gateG[b * H + col];
            tc4[ct]  = tbiasG[b * H + col];
        }
#pragma unroll
        for (int rt = 0; rt < 8; rt++) {
            const float* fnp = feat + (size_t)(bn0 + rt) * H + w * 64 + lq;
            float fnt4[4];
#pragma unroll
            for (int ct = 0; ct < 4; ct++)
                fnt4[ct] = fnp[ct * 16] + tc4[ct];
#pragma unroll
            for (int r = 0; r < 4; r++) {
                int row = rt * 16 + quad * 4 + r;
                const float* rowp = feat + ((size_t)b * NPT + nidxS[row]) * H + w * 64 + lq;
#pragma unroll
                for (int ct = 0; ct < 4; ct++) {
                    float fb = rowp[ct * 16];
                    float emb = fmaxf(acc[rt][ct][r] + b2c4[ct], 0.0f);
                    A[row][w * 64 + ct * 16 + lq] = f2b(fast_tanh(fnt4[ct] + fb + emb * gc4[ct]));
                }
            }
        }
    }
    __syncthreads();

    // GEMM2: C2[128][128] = edge_feat @ We1
    floatx4 acc2[8][2];
#pragma unroll
    for (int rt = 0; rt < 8; rt++)
#pragma unroll
        for (int c2 = 0; c2 < 2; c2++) acc2[rt][c2] = (floatx4){0, 0, 0, 0};
    __builtin_amdgcn_s_setprio(1);
    for (int kt = 0; kt < 8; kt++) {
        shortx8 bf[2];
#pragma unroll
        for (int c2 = 0; c2 < 2; c2++)
            bf[c2] = *(const shortx8*)&we1t[(w * 32 + c2 * 16 + lq) * 256 + kt * 32 + quad * 8];
#pragma unroll
        for (int rt = 0; rt < 8; rt++) {
            shortx8 a = *(const shortx8*)&A[rt * 16 + lq][kt * 32 + quad * 8];
#pragma unroll
            for (int c2 = 0; c2 < 2; c2++)
                acc2[rt][c2] = __builtin_amdgcn_mfma_f32_16x16x32_bf16(a, bf[c2], acc2[rt][c2], 0, 0, 0);
        }
    }
    __builtin_amdgcn_s_setprio(0);

    // logits partials
    float pl[8][4];
#pragma unroll
    for (int rt = 0; rt < 8; rt++)
#pragma unroll
        for (int r = 0; r < 4; r++) pl[rt][r] = 0.0f;
#pragma unroll
    for (int c2 = 0; c2 < 2; c2++) {
        int col = w * 32 + c2 * 16 + lq;
        float be1c = be1[col], w2c = we2[col];
#pragma unroll
        for (int rt = 0; rt < 8; rt++)
#pragma unroll
            for (int r = 0; r < 4; r++)
                pl[rt][r] += fmaxf(acc2[rt][c2][r] + be1c, 0.0f) * w2c;
    }
#pragma unroll
    for (int d = 1; d < 16; d <<= 1)
#pragma unroll
        for (int rt = 0; rt < 8; rt++)
#pragma unroll
            for (int r = 0; r < 4; r++) pl[rt][r] += __shfl_xor(pl[rt][r], d, 16);
    if (lq == 0) {
#pragma unroll
        for (int rt = 0; rt < 8; rt++)
#pragma unroll
            for (int r = 0; r < 4; r++)
                part[w][rt * 16 + quad * 4 + r] = pl[rt][r];
    }
    __syncthreads();
    if (h < 128)
        logitsS[h] = part[0][h] + part[1][h] + part[2][h] + part[3][h] + be2[0];
    __syncthreads();
    if (h < 128) {
        int base = (h >> 4) * 16;
        float mx = -1e30f;
#pragma unroll
        for (int j = 0; j < KNN; j++) mx = fmaxf(mx, logitsS[base + j]);
        float sum = 0.0f;
#pragma unroll
        for (int j = 0; j < KNN; j++) sum += expf(logitsS[base + j] - mx);
        alphaS[h] = expf(logitsS[h] - mx) / sum;
    }
    __syncthreads();

    // ctx: 2 passes; thread -> (point p, 4 cols); bf16 gather over 16 nbrs.
#pragma unroll
    for (int pp = 0; pp < 2; pp++) {
        int p = pp * 4 + (h >> 6), cg = (h & 63) * 4;
        float4 c = {0, 0, 0, 0};
#pragma unroll
        for (int j = 0; j < KNN; j++) {
            float al = alphaS[p * 16 + j];
            const u32* mp = (const u32*)&MSGB[((size_t)b * NPT + nidxS[p * 16 + j]) * H + cg];
            u32 m0 = mp[0], m1 = mp[1];
            c.x += al * __uint_as_float(m0 << 16);
            c.y += al * __uint_as_float(m0 & 0xFFFF0000u);
            c.z += al * __uint_as_float(m1 << 16);
            c.w += al * __uint_as_float(m1 & 0xFFFF0000u);
        }
        uint2 st;
        st.x = (u32)f2b(c.x) | ((u32)f2b(c.y) << 16);
        st.y = (u32)f2b(c.z) | ((u32)f2b(c.w) << 16);
        *(uint2*)&ctxB[(size_t)(bn0 + p) * H + cg] = st;
    }
}

// ---------------------------------------------------------------------------
// K5: out = LN(feat + relu([feat|ctx] @ Wo + bo)), MFMA. R19: M=64
// (256 blocks, wot stream 128->64MB total). acc[4][4]=64 AGPR + x[4][4][4]
// ~170 regs < 256 @ (256,2); LDS 66.5KB.
// ---------------------------------------------------------------------------
__global__ __launch_bounds__(256, 2) void out_mfma(const float* __restrict__ feat,
                                                   const u16* __restrict__ ctxB,
                                                   const u16* __restrict__ wot,
                                                   const float* __restrict__ bo,
                                                   const float* __restrict__ gamma,
                                                   const float* __restrict__ beta,
                                                   float* __restrict__ out) {
    __shared__ __attribute__((aligned(16))) u16 A[64][520];
    __shared__ float redS[4][64], redS2[4][64];
    int p0 = blockIdx.x * 64, h = threadIdx.x;
    int w = h >> 6, lane = h & 63, quad = lane >> 4, lq = lane & 15;
#pragma unroll 8
    for (int row = 0; row < 64; row++) {
        A[row][h]       = f2b(feat[(size_t)(p0 + row) * H + h]);
        A[row][256 + h] = ctxB[(size_t)(p0 + row) * H + h];
    }
    __syncthreads();
    floatx4 acc[4][4];
#pragma unroll
    for (int rt = 0; rt < 4; rt++)
#pragma unroll
        for (int ct = 0; ct < 4; ct++) acc[rt][ct] = (floatx4){0, 0, 0, 0};
    for (int kt = 0; kt < 16; kt++) {
        shortx8 bf[4];
#pragma unroll
        for (int ct = 0; ct < 4; ct++)
            bf[ct] = *(const shortx8*)&wot[(w * 64 + ct * 16 + lq) * 512 + kt * 32 + quad * 8];
#pragma unroll
        for (int rt = 0; rt < 4; rt++) {
            shortx8 a = *(const shortx8*)&A[rt * 16 + lq][kt * 32 + quad * 8];
#pragma unroll
            for (int ct = 0; ct < 4; ct++)
                acc[rt][ct] = __builtin_amdgcn_mfma_f32_16x16x32_bf16(a, bf[ct], acc[rt][ct], 0, 0, 0);
        }
    }
    float x[4][4][4];
    float sm[4][4], sq2[4][4];
#pragma unroll
    for (int rt = 0; rt < 4; rt++)
#pragma unroll
        for (int r = 0; r < 4; r++) { sm[rt][r] = 0.0f; sq2[rt][r] = 0.0f; }
#pragma unroll
    for (int rt = 0; rt < 4; rt++)
#pragma unroll
        for (int ct = 0; ct < 4; ct++) {
            int col = w * 64 + ct * 16 + lq;
            float boc = bo[col];
#pragma unroll
            for (int r = 0; r < 4; r++) {
                int row = rt * 16 + quad * 4 + r;
                float xx = feat[(size_t)(p0 + row) * H + col] +
                           fmaxf(acc[rt][ct][r] + boc, 0.0f);
                x[rt][ct][r] = xx;
                sm[rt][r] += xx;
                sq2[rt][r] += xx * xx;
            }
        }
#pragma unroll
    for (int d = 1; d < 16; d <<= 1)
#pragma unroll
        for (int rt = 0; rt < 4; rt++)
#pragma unroll
            for (int r = 0; r < 4; r++) {
                sm[rt][r] += __shfl_xor(sm[rt][r], d, 16);
                sq2[rt][r] += __shfl_xor(sq2[rt][r], d, 16);
            }
    if (lq == 0) {
#pragma unroll
        for (int rt = 0; rt < 4; rt++)
#pragma unroll
            for (int r = 0; r < 4; r++) {
                redS[w][rt * 16 + quad * 4 + r] = sm[rt][r];
                redS2[w][rt * 16 + quad * 4 + r] = sq2[rt][r];
            }
    }
    __syncthreads();
#pragma unroll
    for (int rt = 0; rt < 4; rt++)
#pragma unroll
        for (int r = 0; r < 4; r++) {
            int row = rt * 16 + quad * 4 + r;
            float s1 = redS[0][row] + redS[1][row] + redS[2][row] + redS[3][row];
            float s2 = redS2[0][row] + redS2[1][row] + redS2[2][row] + redS2[3][row];
            float mu = s1 * (1.0f / H);
            float var = s2 * (1.0f / H) - mu * mu;
            float inv = rsqrtf(fmaxf(var, 0.0f) + 1e-5f);
#pragma unroll
            for (int ct = 0; ct < 4; ct++) {
                int col = w * 64 + ct * 16 + lq;
                out[(size_t)(p0 + row) * H + col] =
                    (x[rt][ct][r] - mu) * inv * gamma[col] + beta[col];
            }
        }
}

// ---------------------------------------------------------------------------
extern "C" void kernel_launch(void* const* d_in, const int* in_sizes, int n_in,
                              void* d_out, int out_size, void* d_ws, size_t ws_size,
                              hipStream_t stream) {
    const float* feat    = (const float*)d_in[0];
    const float* centers = (const float*)d_in[1];
    const float* textg   = (const float*)d_in[2];
    const float* w1      = (const float*)d_in[3];
    const float* b1      = (const float*)d_in[4];
    const float* w2      = (const float*)d_in[5];
    const float* b2      = (const float*)d_in[6];
    const float* wg      = (const float*)d_in[7];
    const float* bg      = (const float*)d_in[8];
    const float* wtb     = (const float*)d_in[9];
    const float* btb     = (const float*)d_in[10];
    const float* we1     = (const float*)d_in[11];
    const float* be1     = (const float*)d_in[12];
    const float* we2     = (const float*)d_in[13];
    const float* be2     = (const float*)d_in[14];
    const float* wm      = (const float*)d_in[15];
    const float* bm      = (const float*)d_in[16];
    const float* wo      = (const float*)d_in[17];
    const float* bo      = (const float*)d_in[18];
    const float* gamma   = (const float*)d_in[19];
    const float* beta    = (const float*)d_in[20];

    char* ws = (char*)d_ws;
    size_t off = 0;
    int* knn     = (int*)(ws + off);   off += (size_t)BB * NPT * KNN * 4;   // 1 MB
    float* gate  = (float*)(ws + off); off += (size_t)BB * H * 4;           // 64 KB
    float* tbias = (float*)(ws + off); off += (size_t)BB * H * 4;           // 64 KB
    u16* MSGB    = (u16*)(ws + off);   off += (size_t)BB * NPT * H * 2;     // 8 MB
    u16* ctxB    = (u16*)(ws + off);   off += (size_t)BB * NPT * H * 2;     // 8 MB
    u16* w2t     = (u16*)(ws + off);   off += (size_t)256 * 256 * 2;        // 128 KB
    u16* we1t    = (u16*)(ws + off);   off += (size_t)128 * 256 * 2;        // 64 KB
    u16* wmt     = (u16*)(ws + off);   off += (size_t)256 * 256 * 2;        // 128 KB
    u16* wot     = (u16*)(ws + off);   off += (size_t)256 * 512 * 2;        // 256 KB
    u16* w1t     = (u16*)(ws + off);   off += (size_t)256 * 32 * 2;         // 16 KB

    prep_kernel<<<73, 256, 0, stream>>>(w2, we1, wm, wo, w1, b1,
                                        w2t, we1t, wmt, wot, w1t);
    knn_kernel<<<256, 256, 0, stream>>>(centers, knn);
    gate_kernel<<<BB, 1024, 0, stream>>>(textg, wg, bg, wtb, btb, gate, tbias);
    msg_mfma<<<BB * NPT / 64, 256, 0, stream>>>(feat, wmt, bm, MSGB);
    edge_mfma<<<BB * NPT / 8, 256, 0, stream>>>(feat, centers, w1t, w2t, b2,
                                                we1t, be1, we2, be2, knn, gate, tbias,
                                                MSGB, ctxB);
    out_mfma<<<BB * NPT / 64, 256, 0, stream>>>(feat, ctxB, wot, bo,
                                                gamma, beta, (float*)d_out);
}